// Round 13
// baseline (315.184 us; speedup 1.0000x reference)
//
#include <hip/hip_runtime.h>
#include <hip/hip_bf16.h>

// Problem constants
#define S_LEN 2048
#define HID   4096
#define NH    32
#define NKV   8
#define DH    128
#define NQKV  ((NH + 2*NKV) * DH)   // 6144

typedef __attribute__((ext_vector_type(8))) short s16x8;
typedef __attribute__((ext_vector_type(4))) short s16x4;
typedef __attribute__((ext_vector_type(4))) float f32x4;

__device__ __forceinline__ short f2bf(float x) {
    union { __hip_bfloat16 b; short s; } u;
    u.b = __float2bfloat16(x);
    return u.s;
}
__device__ __forceinline__ float bf2f(short s) {
    union { unsigned int u; float f; } v;
    v.u = ((unsigned int)(unsigned short)s) << 16;
    return v.f;
}

// async global->LDS, 16B per lane; lds dest = wave-uniform base + lane*16
__device__ __forceinline__ void gload16(const void* g, void* l) {
    __builtin_amdgcn_global_load_lds(
        (const __attribute__((address_space(1))) void*)g,
        (__attribute__((address_space(3))) void*)l,
        16, 0, 0);
}

__device__ __forceinline__ void cstore(float* p, float v) { *p = v; }
__device__ __forceinline__ void cstore(short* p, float v) { *p = f2bf(v); }

// ---------------------------------------------------------------------------
// conversion kernel (R8-measured).
// blocks [0,1536): wqkv f32->bf16 LINEAR (gemm1 B).
// blocks [1536,2048): hs f32->bf16 PERMUTED into MFMA A-fragment order,
// COALESCED writes: chunk c directly indexes output (write = hsp + c*8).
// ---------------------------------------------------------------------------
__global__ __launch_bounds__(256) void convert_hs_wqkv(
        const float* __restrict__ hs, short* __restrict__ hsp,
        const float* __restrict__ wq, short* __restrict__ wqb)
{
    const int bid = blockIdx.x;
    if (bid < 1536) {
        const long n = (long)NQKV * HID;
        long i0 = ((long)bid * 256 + threadIdx.x) * 4;
        long stride = 1536L * 256 * 4;
        for (long i = i0; i < n; i += stride) {
            float4 v = *(const float4*)(wq + i);
            s16x4 o;
            o[0] = f2bf(v.x); o[1] = f2bf(v.y); o[2] = f2bf(v.z); o[3] = f2bf(v.w);
            *(s16x4*)(wqb + i) = o;
        }
        return;
    }
    // hs permute: 1M 16B-chunks; c = (m16*128 + k32)*64 + lane
    const int nchunk = (S_LEN / 16) * (HID / 32) * 64;   // 1,048,576
    for (int c = (bid - 1536) * 256 + threadIdx.x; c < nchunk; c += 512 * 256) {
        int lane = c & 63, k32 = (c >> 6) & 127, m16 = c >> 13;
        int row = m16 * 16 + (lane & 15);
        int k   = k32 * 32 + (lane >> 4) * 8;
        const float4* p = (const float4*)(hs + (long)row * HID + k);
        float4 v0 = p[0], v1 = p[1];
        s16x8 o;
        o[0] = f2bf(v0.x); o[1] = f2bf(v0.y); o[2] = f2bf(v0.z); o[3] = f2bf(v0.w);
        o[4] = f2bf(v1.x); o[5] = f2bf(v1.y); o[6] = f2bf(v1.z); o[7] = f2bf(v1.w);
        *(s16x8*)(hsp + (long)c * 8) = o;
    }
}

// ---------------------------------------------------------------------------
// gemm1 (R7/R11-measured, 98.5us, MfmaUtil 45.9 — best gemm192 variant):
// 128x192-tile bf16 GEMM, C = A * B^T.  A read DIRECTLY from global in
// fragment layout (hsp) — LDS holds B only (2 x 24KB).  One barrier/tile.
// NOTE (R1-R10): seven structural variants all pinned at MfmaUtil 44-46%
// — plateau is structural for this tile family; gemm1 closed.
// ---------------------------------------------------------------------------
template <typename OT>
__global__ __launch_bounds__(256, 2) void gemm192(
        const short* __restrict__ Ap, const short* __restrict__ B,
        OT* __restrict__ C, int M, int N, int K)
{
    __shared__ char lds[49152];   // B only: 2 slots x 24KB
    const int t = threadIdx.x;
    const int w = t >> 6, l = t & 63, g = l >> 4, q16 = l & 15;
    const int wm = w >> 1, wn = w & 1;       // wave grid 2(M) x 2(N)
    const int bx = blockIdx.x, by = blockIdx.y;
    const int NT = K >> 6;                   // 64 at K=4096 (even)

    // B staging global byte offsets (chunk pre-swizzled)
    const int srow = t >> 3;
    const int schunk = (t & 7) ^ (srow & 7);
    unsigned goffB[6];
#pragma unroll
    for (int i = 0; i < 6; ++i)
        goffB[i] = (unsigned)(((bx * 192 + i * 32 + srow) * K) * 2 + schunk * 16);
    const int dstw = w * 1024;

    auto STAGE = [&](int kt) {               // 6 DMA: B 24KB
        char* dB = lds + (kt & 1) * 24576 + dstw;
        const unsigned kb = (unsigned)kt * 128;
#pragma unroll
        for (int i = 0; i < 6; ++i)
            gload16((const char*)B + (goffB[i] + kb), dB + i * 4096);
    };

    // A fragment global byte bases: ((m16*128 + k32)*64 + l)*16
    unsigned aBase[4];
#pragma unroll
    for (int mi = 0; mi < 4; ++mi)
        aBase[mi] = ((unsigned)((by * 8 + wm * 4 + mi) * 128) * 64 + (unsigned)l) * 16;

    // B LDS read offsets (row&7 == q16&7)
    int boff[6];
#pragma unroll
    for (int ni = 0; ni < 6; ++ni) boff[ni] = (wn * 96 + ni * 16 + q16) * 128;
    const int sw0 = ((g) ^ (q16 & 7)) << 4;
    const int sw1 = ((4 + g) ^ (q16 & 7)) << 4;

    f32x4 acc[4][6] = {};
    s16x8 aE[4][2], aO[4][2], b0E[2][2], b0O[2][2], b1[4][2];

    // prologue: STAGE(0) -> A(0) loads -> STAGE(1); vmcnt(6) drains
    // STAGE(0)+A(0), keeps STAGE(1) flying; barrier publishes B(0).
    STAGE(0);
    __builtin_amdgcn_sched_barrier(0);
#pragma unroll
    for (int mi = 0; mi < 4; ++mi)
#pragma unroll
        for (int kk = 0; kk < 2; ++kk)
            aE[mi][kk] = *(const s16x8*)((const char*)Ap + aBase[mi] + kk * 1024);
    __builtin_amdgcn_sched_barrier(0);
    STAGE(1);
    asm volatile("s_waitcnt vmcnt(6)" ::: "memory");
    __builtin_amdgcn_s_barrier();
    {
        const char* B0 = lds;
#pragma unroll
        for (int ni = 0; ni < 2; ++ni) {
            b0E[ni][0] = *(const s16x8*)(B0 + boff[ni] + sw0);
            b0E[ni][1] = *(const s16x8*)(B0 + boff[ni] + sw1);
        }
        asm volatile("s_waitcnt lgkmcnt(0)" ::: "memory");
        __builtin_amdgcn_sched_barrier(0);
    }

#define GB(KT, AC, AN, B0C, B0N, PAR) do {                                    \
    /* 1. b1(t) ds_reads; M0 on pre-loaded regs (zero wait) */                \
    const char* Bc_ = lds + (PAR) * 24576;                                    \
    _Pragma("unroll")                                                         \
    for (int ni = 0; ni < 4; ++ni) {                                          \
        b1[ni][0] = *(const s16x8*)(Bc_ + boff[2 + ni] + sw0);                \
        b1[ni][1] = *(const s16x8*)(Bc_ + boff[2 + ni] + sw1);                \
    }                                                                         \
    __builtin_amdgcn_sched_barrier(0);                                        \
    __builtin_amdgcn_s_setprio(1);                                            \
    _Pragma("unroll")                                                         \
    for (int mi = 0; mi < 4; ++mi)                                            \
    _Pragma("unroll")                                                         \
    for (int ni = 0; ni < 2; ++ni)                                            \
    _Pragma("unroll")                                                         \
    for (int kk = 0; kk < 2; ++kk)                                            \
        acc[mi][ni] = __builtin_amdgcn_mfma_f32_16x16x32_bf16(                \
                AC[mi][kk], B0C[ni][kk], acc[mi][ni], 0, 0, 0);               \
    __builtin_amdgcn_s_setprio(0);                                            \
    /* 2. gates + the ONE barrier: slot t free, B(t+1) published */           \
    asm volatile("s_waitcnt lgkmcnt(0)" ::: "memory");                        \
    __builtin_amdgcn_sched_barrier(0);                                        \
    asm volatile("s_waitcnt vmcnt(0)" ::: "memory");                          \
    __builtin_amdgcn_s_barrier();                                             \
    /* 3. A(t+1) frag loads FIRST, then STAGE(t+2), then b0(t+1) reads */     \
    if ((KT) + 1 < NT) {                                                      \
        _Pragma("unroll")                                                     \
        for (int mi = 0; mi < 4; ++mi)                                        \
        _Pragma("unroll")                                                     \
        for (int kk = 0; kk < 2; ++kk)                                        \
            AN[mi][kk] = *(const s16x8*)((const char*)Ap + aBase[mi]          \
                    + (((KT) + 1) * 2 + kk) * 1024);                          \
    }                                                                         \
    __builtin_amdgcn_sched_barrier(0);                                        \
    if ((KT) + 2 < NT) STAGE((KT) + 2);                                       \
    if ((KT) + 1 < NT) {                                                      \
        const char* Bn_ = lds + ((PAR) ^ 1) * 24576;                          \
        _Pragma("unroll")                                                     \
        for (int ni = 0; ni < 2; ++ni) {                                      \
            B0N[ni][0] = *(const s16x8*)(Bn_ + boff[ni] + sw0);               \
            B0N[ni][1] = *(const s16x8*)(Bn_ + boff[ni] + sw1);               \
        }                                                                     \
    }                                                                         \
    __builtin_amdgcn_sched_barrier(0);                                        \
    /* 4. M1 covers step-3 latency */                                         \
    __builtin_amdgcn_s_setprio(1);                                            \
    _Pragma("unroll")                                                         \
    for (int mi = 0; mi < 4; ++mi)                                            \
    _Pragma("unroll")                                                         \
    for (int ni = 0; ni < 4; ++ni)                                            \
    _Pragma("unroll")                                                         \
    for (int kk = 0; kk < 2; ++kk)                                            \
        acc[mi][2 + ni] = __builtin_amdgcn_mfma_f32_16x16x32_bf16(            \
                AC[mi][kk], b1[ni][kk], acc[mi][2 + ni], 0, 0, 0);            \
    __builtin_amdgcn_s_setprio(0);                                            \
    /* 5. end gates: b0(t+1) in regs; A(t+1) drained, STAGE(t+2) flies */     \
    asm volatile("s_waitcnt lgkmcnt(0)" ::: "memory");                        \
    __builtin_amdgcn_sched_barrier(0);                                        \
    if ((KT) + 2 < NT) asm volatile("s_waitcnt vmcnt(6)" ::: "memory");       \
    else               asm volatile("s_waitcnt vmcnt(0)" ::: "memory");       \
    __builtin_amdgcn_sched_barrier(0);                                        \
} while (0)

    for (int kt = 0; kt < NT; kt += 2) {
        GB(kt,     aE, aO, b0E, b0O, 0);
        GB(kt + 1, aO, aE, b0O, b0E, 1);
    }
#undef GB

    // epilogue: D col = lane&15, row = (lane>>4)*4 + r
#pragma unroll
    for (int mi = 0; mi < 4; ++mi) {
        long row = (long)by * 128 + wm * 64 + mi * 16 + g * 4;
#pragma unroll
        for (int ni = 0; ni < 6; ++ni) {
            long col = (long)bx * 192 + wn * 96 + ni * 16 + q16;
            f32x4 v = acc[mi][ni];
#pragma unroll
            for (int r = 0; r < 4; ++r)
                cstore(&C[(row + r) * (long)N + col], v[r]);
        }
    }
}

// ---------------------------------------------------------------------------
// gemm2: bf16 GEMM, C[M][N] = A[M][K] * B[N][K]^T.  R5 state (kept): 128x128
// tile, 256 threads (4 waves, 2Mx2N, 64x64/wave), counted lgkmcnt(4) gate,
// A-frag readahead dbuf, one barrier per K-tile, 2 blocks/CU.
// ---------------------------------------------------------------------------
template <typename OT>
__global__ __launch_bounds__(256, 2) void gemm_bt(
        const short* __restrict__ A, const short* __restrict__ B,
        OT* __restrict__ C, int M, int N, int K)
{
    __shared__ char lds[65536];   // A: 2 x 16KB at [0,32K); B: 2 x 16KB at [32K,64K)
    const int t = threadIdx.x;
    const int w = t >> 6, l = t & 63, g = l >> 4, q16 = l & 15;
    const int wm = w >> 1, wn = w & 1;       // wave grid 2(M) x 2(N)
    const int bx = blockIdx.x, by = blockIdx.y;
    const int NT = K >> 6;                   // 64 at K=4096 (even)

    // staging global byte offsets (chunk pre-swizzled)
    const int srow = t >> 3;                 // 0..31 within a 32-row band
    const int schunk = (t & 7) ^ (srow & 7);
    unsigned goffA[4], goffB[4];
#pragma unroll
    for (int i = 0; i < 4; ++i) {
        goffA[i] = (unsigned)(((by * 128 + i * 32 + srow) * K) * 2 + schunk * 16);
        goffB[i] = (unsigned)(((bx * 128 + i * 32 + srow) * K) * 2 + schunk * 16);
    }
    const int dstw = w * 1024;               // wave-uniform dest base part

    auto STAGE = [&](int kt) {               // 8 DMA instrs: A 16KB + B 16KB
        const int par = kt & 1;
        char* dA = lds + par * 16384 + dstw;
        char* dB = lds + 32768 + par * 16384 + dstw;
        const unsigned kb = (unsigned)kt * 128;
#pragma unroll
        for (int i = 0; i < 4; ++i) {
            gload16((const char*)A + (goffA[i] + kb), dA + i * 4096);
            gload16((const char*)B + (goffB[i] + kb), dB + i * 4096);
        }
    };

    // LDS read offsets (row&7 == q16&7 everywhere)
    int aoff[4], boff[4];
#pragma unroll
    for (int i = 0; i < 4; ++i) {
        aoff[i] = (wm * 64 + i * 16 + q16) * 128;
        boff[i] = (wn * 64 + i * 16 + q16) * 128;
    }
    const int sw0 = ((g) ^ (q16 & 7)) << 4;
    const int sw1 = ((4 + g) ^ (q16 & 7)) << 4;

    f32x4 acc[4][4] = {};
    s16x8 aE[4][2], aO[4][2], bf[4][2];

    // prologue: stage tiles 0,1; publish tile0; read-ahead A(0) -> aE
    STAGE(0); STAGE(1);
    asm volatile("s_waitcnt vmcnt(8)" ::: "memory");
    __builtin_amdgcn_s_barrier();
    {
        const char* A0 = lds;
#pragma unroll
        for (int mi = 0; mi < 4; ++mi) {
            aE[mi][0] = *(const s16x8*)(A0 + aoff[mi] + sw0);
            aE[mi][1] = *(const s16x8*)(A0 + aoff[mi] + sw1);
        }
    }

#define GB(KT, AC, AN, PAR) do {                                              \
    const char* Bs_ = lds + 32768 + (PAR) * 16384;                            \
    _Pragma("unroll")                                                         \
    for (int ni = 0; ni < 4; ++ni) {                                          \
        bf[ni][0] = *(const s16x8*)(Bs_ + boff[ni] + sw0);                    \
        bf[ni][1] = *(const s16x8*)(Bs_ + boff[ni] + sw1);                    \
    }                                                                         \
    asm volatile("s_waitcnt lgkmcnt(4)" ::: "memory");  /* A + b01 done */    \
    __builtin_amdgcn_sched_barrier(0);                                        \
    __builtin_amdgcn_s_setprio(1);                                            \
    _Pragma("unroll")                                                         \
    for (int mi = 0; mi < 4; ++mi)                                            \
    _Pragma("unroll")                                                         \
    for (int ni = 0; ni < 2; ++ni)                                            \
    _Pragma("unroll")                                                         \
    for (int kk = 0; kk < 2; ++kk)                                            \
        acc[mi][ni] = __builtin_amdgcn_mfma_f32_16x16x32_bf16(                \
                AC[mi][kk], bf[ni][kk], acc[mi][ni], 0, 0, 0);                \
    __builtin_amdgcn_s_setprio(0);                                            \
    asm volatile("s_waitcnt lgkmcnt(0)" ::: "memory");  /* b23 done */        \
    __builtin_amdgcn_sched_barrier(0);                                        \
    asm volatile("s_waitcnt vmcnt(0)" ::: "memory");    /* t+1 resident */    \
    __builtin_amdgcn_s_barrier();   /* slot t free + tile t+1 published */    \
    if ((KT) + 2 < NT) STAGE((KT) + 2);                                       \
    if ((KT) + 1 < NT) {            /* read-ahead A(t+1) under M1 */          \
        const char* An_ = lds + (((PAR) ^ 1) * 16384);                        \
        _Pragma("unroll")                                                     \
        for (int mi = 0; mi < 4; ++mi) {                                      \
            AN[mi][0] = *(const s16x8*)(An_ + aoff[mi] + sw0);                \
            AN[mi][1] = *(const s16x8*)(An_ + aoff[mi] + sw1);                \
        }                                                                     \
    }                                                                         \
    __builtin_amdgcn_s_setprio(1);                                            \
    _Pragma("unroll")                                                         \
    for (int mi = 0; mi < 4; ++mi)                                            \
    _Pragma("unroll")                                                         \
    for (int ni = 0; ni < 2; ++ni)                                            \
    _Pragma("unroll")                                                         \
    for (int kk = 0; kk < 2; ++kk)                                            \
        acc[mi][2 + ni] = __builtin_amdgcn_mfma_f32_16x16x32_bf16(            \
                AC[mi][kk], bf[2 + ni][kk], acc[mi][2 + ni], 0, 0, 0);        \
    __builtin_amdgcn_s_setprio(0);                                            \
} while (0)

    for (int kt = 0; kt < NT; kt += 2) {
        GB(kt,     aE, aO, 0);
        GB(kt + 1, aO, aE, 1);
    }
#undef GB

    // epilogue: D col = lane&15, row = (lane>>4)*4 + r
#pragma unroll
    for (int mi = 0; mi < 4; ++mi) {
        long row = (long)by * 128 + wm * 64 + mi * 16 + g * 4;
#pragma unroll
        for (int ni = 0; ni < 4; ++ni) {
            long col = (long)bx * 128 + wn * 64 + ni * 16 + q16;
            f32x4 v = acc[mi][ni];
#pragma unroll
            for (int r = 0; r < 4; ++r)
                cstore(&C[(row + r) * (long)N + col], v[r]);
        }
    }
}

// ---------------------------------------------------------------------------
// Post-gemm1 kernel, R13: Q norm+rope moved into attn (1:1 producer-consumer
// mapping, zero recompute).  Remaining jobs:
//   blocks [0, 2048):       K RMSNorm+RoPE (block = seq pos, 8 K-slots)
//   blocks [2048, 2560):    V transpose
// ---------------------------------------------------------------------------
__global__ __launch_bounds__(256) void post_gemm1_fused(
        const short* __restrict__ qkvb, const int* __restrict__ pos,
        const float* __restrict__ gk,
        short* __restrict__ ko, short* __restrict__ vt)
{
    const int bid = blockIdx.x;

    if (bid < 2048) {
        // ---- K RMSNorm + RoPE: s = bid, slot = NH + (tid>>5) ----
        const int s = bid;
        const int slot = NH + (threadIdx.x >> 5);   // 32..39
        const int p = threadIdx.x & 31, d = p * 4;

        s16x4 xv = *(const s16x4*)(qkvb + (long)s * NQKV + slot * DH + d);
        float x[4];
#pragma unroll
        for (int r = 0; r < 4; ++r) x[r] = bf2f(xv[r]);

        float ss = x[0]*x[0] + x[1]*x[1] + x[2]*x[2] + x[3]*x[3];
#pragma unroll
        for (int o = 1; o < 32; o <<= 1) ss += __shfl_xor(ss, o);
        float rms = rsqrtf(ss * (1.0f / DH) + 1e-6f);

        float y[4];
#pragma unroll
        for (int r = 0; r < 4; ++r) y[r] = x[r] * rms * gk[d + r];

        float y2[4];
#pragma unroll
        for (int r = 0; r < 4; ++r) y2[r] = __shfl_xor(y[r], 16);

        const float po = (float)pos[s];
        const int jbase = d & 63;
        s16x4 ov;
#pragma unroll
        for (int r = 0; r < 4; ++r) {
            float invf = exp2f(-(float)(jbase + r) * (13.287712379549449f / 64.0f));
            float ang = po * invf;
            float c = cosf(ang), sn = sinf(ang);
            float outv = (d < 64) ? (y[r] * c - y2[r] * sn)
                                  : (y[r] * c + y2[r] * sn);
            ov[r] = f2bf(outv);
        }
        *(s16x4*)(ko + ((long)s * NKV + (slot - NH)) * DH + d) = ov;
        return;
    }

    // ---- V transpose: qkvb v-slots -> vt[h][d][s], 64x64 LDS tiles ----
    __shared__ short tile[64][72];
    const int idx2 = bid - 2048;
    const int sb = idx2 & 31, db = (idx2 >> 5) & 1, h = idx2 >> 6;
    const int t = threadIdx.x;
#pragma unroll
    for (int i = 0; i < 2; ++i) {
        int c = i * 256 + t;
        int row = c >> 3, dc = (c & 7) * 8;
        const short* src = qkvb + (long)(sb*64 + row) * NQKV
                           + (NH + NKV + h) * DH + db*64 + dc;
        s16x8 x = *(const s16x8*)src;
#pragma unroll
        for (int jj = 0; jj < 8; ++jj) tile[row][dc + jj] = x[jj];
    }
    __syncthreads();
#pragma unroll
    for (int i = 0; i < 2; ++i) {
        int c = i * 256 + t;
        int dr = c >> 3, sc = (c & 7) * 8;
        s16x8 y;
#pragma unroll
        for (int jj = 0; jj < 8; ++jj) y[jj] = tile[sc + jj][dr];
        short* dst = vt + (long)(h*DH + db*64 + dr) * S_LEN + sb*64 + sc;
        *(s16x8*)dst = y;
    }
}

// ---------------------------------------------------------------------------
// stage one K tile [64][128] and one Vt tile [128][64] into LDS via
// global_load_lds, PRE-SWIZZLED global source (+ linear LDS dest).
// V staging is PREFETCH (fire-and-forget DMA a tile ahead).
// ---------------------------------------------------------------------------
__device__ __forceinline__ void stage_kv(const char* kgB, const char* vgB,
                                         int kt, int t, char* kd, char* vd)
{
    const int w = t >> 6;
#pragma unroll
    for (int ci = 0; ci < 4; ++ci) {
        int c = ci * 256 + t;
        int row = c >> 4, col16 = c & 15;
        const char* gk = kgB + (long)(kt*64 + row) * (NKV*DH*2)
                         + ((col16*16) ^ ((row & 7) << 4));
        gload16(gk, kd + ci*4096 + w*1024);
        int rowv = c >> 3, scol8 = c & 7;
        const char* gv = vgB + (long)rowv * (S_LEN*2) + kt*128
                         + ((scol8*16) ^ ((rowv & 7) << 4));
        gload16(gv, vd + ci*4096 + w*1024);
    }
}

// ---------------------------------------------------------------------------
// Causal GQA flash attention, v12 + R12 (wo-convert tail blocks) + R13
// (Q RMSNorm+RoPE fused into the Q-load prologue — reads raw qkvb, norms
// and ropes in-register, hidden under the first stage_kv's HBM latency).
// ---------------------------------------------------------------------------
__global__ __launch_bounds__(256, 2) void attn_kernel(
        const float* __restrict__ wo, short* __restrict__ wob,
        const short* __restrict__ qkvb, const int* __restrict__ pos,
        const float* __restrict__ gq,
        const short* __restrict__ kg, const short* __restrict__ vtg,
        short* __restrict__ ctx)
{
    const int bx = blockIdx.x;       // [0,512) attn; [512,2560) wo-convert
    if (bx >= 512) {
        const long n = (long)HID * (NH * DH);
        long i0 = ((long)(bx - 512) * 256 + threadIdx.x) * 4;
        long stride = 2048L * 256 * 4;
        for (long i = i0; i < n; i += stride) {
            float4 v = *(const float4*)(wo + i);
            s16x4 o;
            o[0] = f2bf(v.x); o[1] = f2bf(v.y); o[2] = f2bf(v.z); o[3] = f2bf(v.w);
            *(s16x4*)(wob + i) = o;
        }
        return;
    }

    const int h  = bx & 31;          // head
    const int slot = bx >> 5;        // 0..15
    const int qb = (slot < 8) ? slot : 23 - slot;   // complementary pairing
    const int kvh = h >> 2;          // GQA: rep=4
    const int t = threadIdx.x, w = t >> 6, l = t & 63, g = l >> 4, q16 = l & 15;

    __shared__ char Kl[2][16384];    // [kv64][d128] bf16, swizzled
    __shared__ char Vl[2][16384];    // [d128][kv64] bf16, swizzled
    __shared__ short Pl[4][32 * 64]; // per-wave P[32 q][64 kv], swizzled

    const float scale = 0.08838834764831845f;  // 1/sqrt(128)
    const char* kgB = (const char*)kg + (long)kvh * DH * 2;
    const char* vgB = (const char*)vtg + (long)kvh * DH * (long)S_LEN * 2;

    const int nt = 2 * qb + 2;               // kv-tiles of 64
    int qrow[2];
    qrow[0] = qb*128 + w*32 + q16;
    qrow[1] = qrow[0] + 16;

    // start K/V staging FIRST — Q norm/rope math hides under its latency
    stage_kv(kgB, vgB, 0, t, Kl[0], Vl[0]);

    // ---- R13: fused Q load + RMSNorm + RoPE (raw qkvb -> bf16 frags) ----
    // lane (g,q16) holds row qrow[s], cols dk*32 + g*8 + j (j=0..7).
    // rope pairs (d, d+64): partner of dk in {0,1} is dk+2 (same lane).
    float gqv[4][8];
#pragma unroll
    for (int dk = 0; dk < 4; ++dk) {
        float4 a = *(const float4*)(gq + dk*32 + g*8);
        float4 b = *(const float4*)(gq + dk*32 + g*8 + 4);
        gqv[dk][0]=a.x; gqv[dk][1]=a.y; gqv[dk][2]=a.z; gqv[dk][3]=a.w;
        gqv[dk][4]=b.x; gqv[dk][5]=b.y; gqv[dk][6]=b.z; gqv[dk][7]=b.w;
    }
    s16x8 qf[2][4];
#pragma unroll
    for (int s = 0; s < 2; ++s) {
        const short* qptr = qkvb + (long)qrow[s] * NQKV + h * DH;
        float e[4][8];
        float ssum = 0.f;
#pragma unroll
        for (int dk = 0; dk < 4; ++dk) {
            s16x8 v = *(const s16x8*)(qptr + dk*32 + g*8);
#pragma unroll
            for (int j = 0; j < 8; ++j) {
                float x = bf2f(v[j]);
                e[dk][j] = x;
                ssum += x * x;
            }
        }
        ssum += __shfl_xor(ssum, 16);
        ssum += __shfl_xor(ssum, 32);
        float rms = rsqrtf(ssum * (1.0f / DH) + 1e-6f);
        float po = (float)pos[qrow[s]];
#pragma unroll
        for (int dk = 0; dk < 2; ++dk)
#pragma unroll
            for (int j = 0; j < 8; ++j) {
                int jb = dk*32 + g*8 + j;
                float invf = exp2f(-(float)jb * (13.287712379549449f / 64.0f));
                float ang = po * invf;
                float c = cosf(ang), sn = sinf(ang);
                float y1 = e[dk][j]     * rms * gqv[dk][j];
                float y2 = e[dk + 2][j] * rms * gqv[dk + 2][j];
                qf[s][dk][j]     = f2bf(y1 * c - y2 * sn);
                qf[s][dk + 2][j] = f2bf(y2 * c + y1 * sn);
            }
    }

    f32x4 oacc[2][8] = {};
    float m_run[2] = {-1e30f, -1e30f}, l_run[2] = {0.f, 0.f};

    __syncthreads();   // drain vmcnt -> buf0 ready

    for (int kt = 0; kt < nt; ++kt) {
        const int b = kt & 1;
        if (kt + 1 < nt)   // prefetch next tile into other buffer (async)
            stage_kv(kgB, vgB, kt + 1, t, Kl[b ^ 1], Vl[b ^ 1]);
        const char* kb = Kl[b];
        const char* vbb = Vl[b];

        // ---- QK^T swapped: S^T[kv][q] = K * Q^T; K-frags serve both s
        f32x4 sacc[2][4] = {};
        __builtin_amdgcn_s_setprio(1);
#pragma unroll
        for (int m = 0; m < 4; ++m) {
            int kvr = m*16 + q16;
            s16x8 af[4];
#pragma unroll
            for (int dk = 0; dk < 4; ++dk) {
                int byte = (kvr*256 + (dk*32 + g*8)*2) ^ ((kvr & 7) << 4);
                af[dk] = *(const s16x8*)(kb + byte);
            }
#pragma unroll
            for (int s = 0; s < 2; ++s)
#pragma unroll
                for (int dk = 0; dk < 4; ++dk)
                    sacc[s][m] = __builtin_amdgcn_mfma_f32_16x16x32_bf16(
                            af[dk], qf[s][dk], sacc[s][m], 0,0,0);
        }
        __builtin_amdgcn_s_setprio(0);

        // ---- online softmax; lane owns q-columns qrow[0], qrow[1] ----
        const bool diag = (kt >= 2*qb);      // last two tiles straddle diag
        float mx[2];
#pragma unroll
        for (int s = 0; s < 2; ++s) {
            mx[s] = -1e30f;
#pragma unroll
            for (int m = 0; m < 4; ++m)
#pragma unroll
                for (int r = 0; r < 4; ++r) {
                    float x = sacc[s][m][r] * scale;
                    if (diag) {
                        int kv = kt*64 + m*16 + g*4 + r;
                        if (kv > qrow[s]) x = -1e30f;
                    }
                    sacc[s][m][r] = x;
                    mx[s] = fmaxf(mx[s], x);
                }
            mx[s] = fmaxf(mx[s], __shfl_xor(mx[s], 16));
            mx[s] = fmaxf(mx[s], __shfl_xor(mx[s], 32));
        }
        // defer-max: only rescale when max grew by > 8 somewhere (T13)
        if (__any((mx[0] > m_run[0] + 8.f) || (mx[1] > m_run[1] + 8.f))) {
#pragma unroll
            for (int s = 0; s < 2; ++s) {
                float m_new = fmaxf(m_run[s], mx[s]);
                float corr = __expf(m_run[s] - m_new);
                l_run[s] *= corr;
                m_run[s] = m_new;
                float rf[4];
#pragma unroll
                for (int r = 0; r < 4; ++r)
                    rf[r] = __shfl(corr, (g << 4) | (g*4 + r));
#pragma unroll
                for (int nf = 0; nf < 8; ++nf)
#pragma unroll
                    for (int r = 0; r < 4; ++r) oacc[s][nf][r] *= rf[r];
            }
        }
        // exp + pack to bf16 + LDS write (P bounded by e^8 when deferred)
#pragma unroll
        for (int s = 0; s < 2; ++s) {
            float psum = 0.f;
#pragma unroll
            for (int m = 0; m < 4; ++m) {
                s16x4 pk;
#pragma unroll
                for (int r = 0; r < 4; ++r) {
                    float e = __expf(sacc[s][m][r] - m_run[s]);
                    psum += e;
                    pk[r] = f2bf(e);
                }
                int byte = ((s*16 + q16)*128 + (m*16 + g*4)*2) ^ ((q16 & 7) << 4);
                *(s16x4*)((char*)&Pl[w][0] + byte) = pk;
            }
            psum += __shfl_xor(psum, 16);
            psum += __shfl_xor(psum, 32);
            l_run[s] += psum;
        }

        // ---- PV: O[q][d] += P[q][kv] * V[kv][d]; V-frags serve both s
        __builtin_amdgcn_s_setprio(1);
#pragma unroll
        for (int ks = 0; ks < 2; ++ks) {
            s16x8 pa[2];
#pragma unroll
            for (int s = 0; s < 2; ++s) {
                int pbyte = ((s*16 + q16)*128 + (ks*32 + g*8)*2) ^ ((q16 & 7) << 4);
                pa[s] = *(const s16x8*)((const char*)&Pl[w][0] + pbyte);
            }
#pragma unroll
            for (int nf = 0; nf < 8; ++nf) {
                int drow = nf*16 + q16;
                int vbyte = (drow*128 + (ks*32 + g*8)*2) ^ ((drow & 7) << 4);
                s16x8 vbf = *(const s16x8*)(vbb + vbyte);
#pragma unroll
                for (int s = 0; s < 2; ++s)
                    oacc[s][nf] = __builtin_amdgcn_mfma_f32_16x16x32_bf16(
                            pa[s], vbf, oacc[s][nf], 0,0,0);
            }
        }
        __builtin_amdgcn_s_setprio(0);
        __syncthreads();   // tile done; prefetched buffer complete
    }

    // ---- epilogue: divide by l, write ctx[row][h*128 + d] bf16 ----
#pragma unroll
    for (int s = 0; s < 2; ++s) {
        float lr[4];
#pragma unroll
        for (int r = 0; r < 4; ++r)
            lr[r] = __shfl(l_run[s], (g << 4) | (g*4 + r));
#pragma unroll
        for (int nf = 0; nf < 8; ++nf)
#pragma unroll
            for (int r = 0; r < 4; ++r) {
                int row = qb*128 + w*32 + s*16 + g*4 + r;
                int col = h*DH + nf*16 + q16;
                float val = oacc[s][nf][r] / lr[r];
                ctx[(long)row * (NH*DH) + col] = f2bf(val);
            }
    }
}

// ---------------------------------------------------------------------------
// Workspace layout (race-free, peak 111 MB):
//   [0,16)    hsb (gemm1 A, PERMUTED fragment layout, 16MB exactly)
//             -> ctxb (attn out) after gemm1 consumed it
//   [16,67)   wqkvb (gemm1 B, 50.3MB) -> wob (32MB, written during attn
//             launch by trailing convert blocks — wqkvb dead after gemm1)
//   [48,52)   vtbuf (4MB, written after gemm1)
//   [67,91)   qkvb (gemm1 bf16 out, 24MB; attn reads Q from it directly)
//   [91,107)  qbuf (unused since R13)
//   [107,111) kbuf (4MB)
// ---------------------------------------------------------------------------
extern "C" void kernel_launch(void* const* d_in, const int* in_sizes, int n_in,
                              void* d_out, int out_size, void* d_ws, size_t ws_size,
                              hipStream_t stream)
{
    const int*   positions = (const int*)  d_in[0];
    const float* hs        = (const float*)d_in[1];
    const float* wqkv      = (const float*)d_in[2];
    const float* wo        = (const float*)d_in[3];
    const float* gq        = (const float*)d_in[4];
    const float* gk        = (const float*)d_in[5];
    float* out = (float*)d_out;
    char* ws = (char*)d_ws;

    const size_t MB = 1ull << 20;
    short* hsb   = (short*)(ws);
    short* ctxb  = (short*)(ws);
    short* wqkvb = (short*)(ws + 16*MB);
    short* wob   = (short*)(ws + 16*MB);
    short* vtbuf = (short*)(ws + 48*MB);
    short* qkvb  = (short*)(ws + 67*MB);
    short* kbuf  = (short*)(ws + 107*MB);

    (void)in_sizes; (void)n_in; (void)out_size; (void)ws_size;

    convert_hs_wqkv<<<2048, 256, 0, stream>>>(hs, hsb, wqkv, wqkvb);
    gemm192<short><<<dim3(NQKV/192, S_LEN/128), 256, 0, stream>>>(
            hsb, wqkvb, qkvb, S_LEN, NQKV, HID);
    post_gemm1_fused<<<2560, 256, 0, stream>>>(
            qkvb, positions, gk, kbuf, vtbuf);
    attn_kernel<<<dim3(2560), 256, 0, stream>>>(
            wo, wob, qkvb, positions, gq, kbuf, vtbuf, ctxb);
    gemm_bt<float><<<dim3(HID/128, S_LEN/128), 256, 0, stream>>>(
            ctxb, wob, out, S_LEN, HID, HID);
}

// Round 14
// 314.898 us; speedup vs baseline: 1.0009x; 1.0009x over previous
//
#include <hip/hip_runtime.h>
#include <hip/hip_bf16.h>

// Problem constants
#define S_LEN 2048
#define HID   4096
#define NH    32
#define NKV   8
#define DH    128
#define NQKV  ((NH + 2*NKV) * DH)   // 6144

typedef __attribute__((ext_vector_type(8))) short s16x8;
typedef __attribute__((ext_vector_type(4))) short s16x4;
typedef __attribute__((ext_vector_type(4))) float f32x4;

__device__ __forceinline__ short f2bf(float x) {
    union { __hip_bfloat16 b; short s; } u;
    u.b = __float2bfloat16(x);
    return u.s;
}
__device__ __forceinline__ float bf2f(short s) {
    union { unsigned int u; float f; } v;
    v.u = ((unsigned int)(unsigned short)s) << 16;
    return v.f;
}

// async global->LDS, 16B per lane; lds dest = wave-uniform base + lane*16
__device__ __forceinline__ void gload16(const void* g, void* l) {
    __builtin_amdgcn_global_load_lds(
        (const __attribute__((address_space(1))) void*)g,
        (__attribute__((address_space(3))) void*)l,
        16, 0, 0);
}

__device__ __forceinline__ void cstore(float* p, float v) { *p = v; }
__device__ __forceinline__ void cstore(short* p, float v) { *p = f2bf(v); }

// ---------------------------------------------------------------------------
// conversion kernel (R8-measured).
// blocks [0,1536): wqkv f32->bf16 LINEAR (gemm1 B).
// blocks [1536,2048): hs f32->bf16 PERMUTED into MFMA A-fragment order,
// COALESCED writes: chunk c directly indexes output (write = hsp + c*8).
// ---------------------------------------------------------------------------
__global__ __launch_bounds__(256) void convert_hs_wqkv(
        const float* __restrict__ hs, short* __restrict__ hsp,
        const float* __restrict__ wq, short* __restrict__ wqb)
{
    const int bid = blockIdx.x;
    if (bid < 1536) {
        const long n = (long)NQKV * HID;
        long i0 = ((long)bid * 256 + threadIdx.x) * 4;
        long stride = 1536L * 256 * 4;
        for (long i = i0; i < n; i += stride) {
            float4 v = *(const float4*)(wq + i);
            s16x4 o;
            o[0] = f2bf(v.x); o[1] = f2bf(v.y); o[2] = f2bf(v.z); o[3] = f2bf(v.w);
            *(s16x4*)(wqb + i) = o;
        }
        return;
    }
    // hs permute: 1M 16B-chunks; c = (m16*128 + k32)*64 + lane
    const int nchunk = (S_LEN / 16) * (HID / 32) * 64;   // 1,048,576
    for (int c = (bid - 1536) * 256 + threadIdx.x; c < nchunk; c += 512 * 256) {
        int lane = c & 63, k32 = (c >> 6) & 127, m16 = c >> 13;
        int row = m16 * 16 + (lane & 15);
        int k   = k32 * 32 + (lane >> 4) * 8;
        const float4* p = (const float4*)(hs + (long)row * HID + k);
        float4 v0 = p[0], v1 = p[1];
        s16x8 o;
        o[0] = f2bf(v0.x); o[1] = f2bf(v0.y); o[2] = f2bf(v0.z); o[3] = f2bf(v0.w);
        o[4] = f2bf(v1.x); o[5] = f2bf(v1.y); o[6] = f2bf(v1.z); o[7] = f2bf(v1.w);
        *(s16x8*)(hsp + (long)c * 8) = o;
    }
}

// ---------------------------------------------------------------------------
// gemm1 (R7/R11-measured, 98.5us, MfmaUtil 45.9 — best gemm192 variant):
// 128x192-tile bf16 GEMM, C = A * B^T.  A read DIRECTLY from global in
// fragment layout (hsp) — LDS holds B only (2 x 24KB).  One barrier/tile.
// NOTE (R1-R10): seven structural variants all pinned at MfmaUtil 44-46%
// — plateau is structural for this tile family; gemm1 closed.
// ---------------------------------------------------------------------------
template <typename OT>
__global__ __launch_bounds__(256, 2) void gemm192(
        const short* __restrict__ Ap, const short* __restrict__ B,
        OT* __restrict__ C, int M, int N, int K)
{
    __shared__ char lds[49152];   // B only: 2 slots x 24KB
    const int t = threadIdx.x;
    const int w = t >> 6, l = t & 63, g = l >> 4, q16 = l & 15;
    const int wm = w >> 1, wn = w & 1;       // wave grid 2(M) x 2(N)
    const int bx = blockIdx.x, by = blockIdx.y;
    const int NT = K >> 6;                   // 64 at K=4096 (even)

    // B staging global byte offsets (chunk pre-swizzled)
    const int srow = t >> 3;
    const int schunk = (t & 7) ^ (srow & 7);
    unsigned goffB[6];
#pragma unroll
    for (int i = 0; i < 6; ++i)
        goffB[i] = (unsigned)(((bx * 192 + i * 32 + srow) * K) * 2 + schunk * 16);
    const int dstw = w * 1024;

    auto STAGE = [&](int kt) {               // 6 DMA: B 24KB
        char* dB = lds + (kt & 1) * 24576 + dstw;
        const unsigned kb = (unsigned)kt * 128;
#pragma unroll
        for (int i = 0; i < 6; ++i)
            gload16((const char*)B + (goffB[i] + kb), dB + i * 4096);
    };

    // A fragment global byte bases: ((m16*128 + k32)*64 + l)*16
    unsigned aBase[4];
#pragma unroll
    for (int mi = 0; mi < 4; ++mi)
        aBase[mi] = ((unsigned)((by * 8 + wm * 4 + mi) * 128) * 64 + (unsigned)l) * 16;

    // B LDS read offsets (row&7 == q16&7)
    int boff[6];
#pragma unroll
    for (int ni = 0; ni < 6; ++ni) boff[ni] = (wn * 96 + ni * 16 + q16) * 128;
    const int sw0 = ((g) ^ (q16 & 7)) << 4;
    const int sw1 = ((4 + g) ^ (q16 & 7)) << 4;

    f32x4 acc[4][6] = {};
    s16x8 aE[4][2], aO[4][2], b0E[2][2], b0O[2][2], b1[4][2];

    // prologue: STAGE(0) -> A(0) loads -> STAGE(1); vmcnt(6) drains
    // STAGE(0)+A(0), keeps STAGE(1) flying; barrier publishes B(0).
    STAGE(0);
    __builtin_amdgcn_sched_barrier(0);
#pragma unroll
    for (int mi = 0; mi < 4; ++mi)
#pragma unroll
        for (int kk = 0; kk < 2; ++kk)
            aE[mi][kk] = *(const s16x8*)((const char*)Ap + aBase[mi] + kk * 1024);
    __builtin_amdgcn_sched_barrier(0);
    STAGE(1);
    asm volatile("s_waitcnt vmcnt(6)" ::: "memory");
    __builtin_amdgcn_s_barrier();
    {
        const char* B0 = lds;
#pragma unroll
        for (int ni = 0; ni < 2; ++ni) {
            b0E[ni][0] = *(const s16x8*)(B0 + boff[ni] + sw0);
            b0E[ni][1] = *(const s16x8*)(B0 + boff[ni] + sw1);
        }
        asm volatile("s_waitcnt lgkmcnt(0)" ::: "memory");
        __builtin_amdgcn_sched_barrier(0);
    }

#define GB(KT, AC, AN, B0C, B0N, PAR) do {                                    \
    /* 1. b1(t) ds_reads; M0 on pre-loaded regs (zero wait) */                \
    const char* Bc_ = lds + (PAR) * 24576;                                    \
    _Pragma("unroll")                                                         \
    for (int ni = 0; ni < 4; ++ni) {                                          \
        b1[ni][0] = *(const s16x8*)(Bc_ + boff[2 + ni] + sw0);                \
        b1[ni][1] = *(const s16x8*)(Bc_ + boff[2 + ni] + sw1);                \
    }                                                                         \
    __builtin_amdgcn_sched_barrier(0);                                        \
    __builtin_amdgcn_s_setprio(1);                                            \
    _Pragma("unroll")                                                         \
    for (int mi = 0; mi < 4; ++mi)                                            \
    _Pragma("unroll")                                                         \
    for (int ni = 0; ni < 2; ++ni)                                            \
    _Pragma("unroll")                                                         \
    for (int kk = 0; kk < 2; ++kk)                                            \
        acc[mi][ni] = __builtin_amdgcn_mfma_f32_16x16x32_bf16(                \
                AC[mi][kk], B0C[ni][kk], acc[mi][ni], 0, 0, 0);               \
    __builtin_amdgcn_s_setprio(0);                                            \
    /* 2. gates + the ONE barrier: slot t free, B(t+1) published */           \
    asm volatile("s_waitcnt lgkmcnt(0)" ::: "memory");                        \
    __builtin_amdgcn_sched_barrier(0);                                        \
    asm volatile("s_waitcnt vmcnt(0)" ::: "memory");                          \
    __builtin_amdgcn_s_barrier();                                             \
    /* 3. A(t+1) frag loads FIRST, then STAGE(t+2), then b0(t+1) reads */     \
    if ((KT) + 1 < NT) {                                                      \
        _Pragma("unroll")                                                     \
        for (int mi = 0; mi < 4; ++mi)                                        \
        _Pragma("unroll")                                                     \
        for (int kk = 0; kk < 2; ++kk)                                        \
            AN[mi][kk] = *(const s16x8*)((const char*)Ap + aBase[mi]          \
                    + (((KT) + 1) * 2 + kk) * 1024);                          \
    }                                                                         \
    __builtin_amdgcn_sched_barrier(0);                                        \
    if ((KT) + 2 < NT) STAGE((KT) + 2);                                       \
    if ((KT) + 1 < NT) {                                                      \
        const char* Bn_ = lds + ((PAR) ^ 1) * 24576;                          \
        _Pragma("unroll")                                                     \
        for (int ni = 0; ni < 2; ++ni) {                                      \
            B0N[ni][0] = *(const s16x8*)(Bn_ + boff[ni] + sw0);               \
            B0N[ni][1] = *(const s16x8*)(Bn_ + boff[ni] + sw1);               \
        }                                                                     \
    }                                                                         \
    __builtin_amdgcn_sched_barrier(0);                                        \
    /* 4. M1 covers step-3 latency */                                         \
    __builtin_amdgcn_s_setprio(1);                                            \
    _Pragma("unroll")                                                         \
    for (int mi = 0; mi < 4; ++mi)                                            \
    _Pragma("unroll")                                                         \
    for (int ni = 0; ni < 4; ++ni)                                            \
    _Pragma("unroll")                                                         \
    for (int kk = 0; kk < 2; ++kk)                                            \
        acc[mi][2 + ni] = __builtin_amdgcn_mfma_f32_16x16x32_bf16(            \
                AC[mi][kk], b1[ni][kk], acc[mi][2 + ni], 0, 0, 0);            \
    __builtin_amdgcn_s_setprio(0);                                            \
    /* 5. end gates: b0(t+1) in regs; A(t+1) drained, STAGE(t+2) flies */     \
    asm volatile("s_waitcnt lgkmcnt(0)" ::: "memory");                        \
    __builtin_amdgcn_sched_barrier(0);                                        \
    if ((KT) + 2 < NT) asm volatile("s_waitcnt vmcnt(6)" ::: "memory");       \
    else               asm volatile("s_waitcnt vmcnt(0)" ::: "memory");       \
    __builtin_amdgcn_sched_barrier(0);                                        \
} while (0)

    for (int kt = 0; kt < NT; kt += 2) {
        GB(kt,     aE, aO, b0E, b0O, 0);
        GB(kt + 1, aO, aE, b0O, b0E, 1);
    }
#undef GB

    // epilogue: D col = lane&15, row = (lane>>4)*4 + r
#pragma unroll
    for (int mi = 0; mi < 4; ++mi) {
        long row = (long)by * 128 + wm * 64 + mi * 16 + g * 4;
#pragma unroll
        for (int ni = 0; ni < 6; ++ni) {
            long col = (long)bx * 192 + wn * 96 + ni * 16 + q16;
            f32x4 v = acc[mi][ni];
#pragma unroll
            for (int r = 0; r < 4; ++r)
                cstore(&C[(row + r) * (long)N + col], v[r]);
        }
    }
}

// ---------------------------------------------------------------------------
// gemm2: bf16 GEMM, C[M][N] = A[M][K] * B[N][K]^T.  R5 state (kept): 128x128
// tile, 256 threads (4 waves, 2Mx2N, 64x64/wave), counted lgkmcnt(4) gate,
// A-frag readahead dbuf, one barrier per K-tile, 2 blocks/CU.
// ---------------------------------------------------------------------------
template <typename OT>
__global__ __launch_bounds__(256, 2) void gemm_bt(
        const short* __restrict__ A, const short* __restrict__ B,
        OT* __restrict__ C, int M, int N, int K)
{
    __shared__ char lds[65536];   // A: 2 x 16KB at [0,32K); B: 2 x 16KB at [32K,64K)
    const int t = threadIdx.x;
    const int w = t >> 6, l = t & 63, g = l >> 4, q16 = l & 15;
    const int wm = w >> 1, wn = w & 1;       // wave grid 2(M) x 2(N)
    const int bx = blockIdx.x, by = blockIdx.y;
    const int NT = K >> 6;                   // 64 at K=4096 (even)

    // staging global byte offsets (chunk pre-swizzled)
    const int srow = t >> 3;                 // 0..31 within a 32-row band
    const int schunk = (t & 7) ^ (srow & 7);
    unsigned goffA[4], goffB[4];
#pragma unroll
    for (int i = 0; i < 4; ++i) {
        goffA[i] = (unsigned)(((by * 128 + i * 32 + srow) * K) * 2 + schunk * 16);
        goffB[i] = (unsigned)(((bx * 128 + i * 32 + srow) * K) * 2 + schunk * 16);
    }
    const int dstw = w * 1024;               // wave-uniform dest base part

    auto STAGE = [&](int kt) {               // 8 DMA instrs: A 16KB + B 16KB
        const int par = kt & 1;
        char* dA = lds + par * 16384 + dstw;
        char* dB = lds + 32768 + par * 16384 + dstw;
        const unsigned kb = (unsigned)kt * 128;
#pragma unroll
        for (int i = 0; i < 4; ++i) {
            gload16((const char*)A + (goffA[i] + kb), dA + i * 4096);
            gload16((const char*)B + (goffB[i] + kb), dB + i * 4096);
        }
    };

    // LDS read offsets (row&7 == q16&7 everywhere)
    int aoff[4], boff[4];
#pragma unroll
    for (int i = 0; i < 4; ++i) {
        aoff[i] = (wm * 64 + i * 16 + q16) * 128;
        boff[i] = (wn * 64 + i * 16 + q16) * 128;
    }
    const int sw0 = ((g) ^ (q16 & 7)) << 4;
    const int sw1 = ((4 + g) ^ (q16 & 7)) << 4;

    f32x4 acc[4][4] = {};
    s16x8 aE[4][2], aO[4][2], bf[4][2];

    // prologue: stage tiles 0,1; publish tile0; read-ahead A(0) -> aE
    STAGE(0); STAGE(1);
    asm volatile("s_waitcnt vmcnt(8)" ::: "memory");
    __builtin_amdgcn_s_barrier();
    {
        const char* A0 = lds;
#pragma unroll
        for (int mi = 0; mi < 4; ++mi) {
            aE[mi][0] = *(const s16x8*)(A0 + aoff[mi] + sw0);
            aE[mi][1] = *(const s16x8*)(A0 + aoff[mi] + sw1);
        }
    }

#define GB(KT, AC, AN, PAR) do {                                              \
    const char* Bs_ = lds + 32768 + (PAR) * 16384;                            \
    _Pragma("unroll")                                                         \
    for (int ni = 0; ni < 4; ++ni) {                                          \
        bf[ni][0] = *(const s16x8*)(Bs_ + boff[ni] + sw0);                    \
        bf[ni][1] = *(const s16x8*)(Bs_ + boff[ni] + sw1);                    \
    }                                                                         \
    asm volatile("s_waitcnt lgkmcnt(4)" ::: "memory");  /* A + b01 done */    \
    __builtin_amdgcn_sched_barrier(0);                                        \
    __builtin_amdgcn_s_setprio(1);                                            \
    _Pragma("unroll")                                                         \
    for (int mi = 0; mi < 4; ++mi)                                            \
    _Pragma("unroll")                                                         \
    for (int ni = 0; ni < 2; ++ni)                                            \
    _Pragma("unroll")                                                         \
    for (int kk = 0; kk < 2; ++kk)                                            \
        acc[mi][ni] = __builtin_amdgcn_mfma_f32_16x16x32_bf16(                \
                AC[mi][kk], bf[ni][kk], acc[mi][ni], 0, 0, 0);                \
    __builtin_amdgcn_s_setprio(0);                                            \
    asm volatile("s_waitcnt lgkmcnt(0)" ::: "memory");  /* b23 done */        \
    __builtin_amdgcn_sched_barrier(0);                                        \
    asm volatile("s_waitcnt vmcnt(0)" ::: "memory");    /* t+1 resident */    \
    __builtin_amdgcn_s_barrier();   /* slot t free + tile t+1 published */    \
    if ((KT) + 2 < NT) STAGE((KT) + 2);                                       \
    if ((KT) + 1 < NT) {            /* read-ahead A(t+1) under M1 */          \
        const char* An_ = lds + (((PAR) ^ 1) * 16384);                        \
        _Pragma("unroll")                                                     \
        for (int mi = 0; mi < 4; ++mi) {                                      \
            AN[mi][0] = *(const s16x8*)(An_ + aoff[mi] + sw0);                \
            AN[mi][1] = *(const s16x8*)(An_ + aoff[mi] + sw1);                \
        }                                                                     \
    }                                                                         \
    __builtin_amdgcn_s_setprio(1);                                            \
    _Pragma("unroll")                                                         \
    for (int mi = 0; mi < 4; ++mi)                                            \
    _Pragma("unroll")                                                         \
    for (int ni = 0; ni < 2; ++ni)                                            \
    _Pragma("unroll")                                                         \
    for (int kk = 0; kk < 2; ++kk)                                            \
        acc[mi][2 + ni] = __builtin_amdgcn_mfma_f32_16x16x32_bf16(            \
                AC[mi][kk], bf[2 + ni][kk], acc[mi][2 + ni], 0, 0, 0);        \
    __builtin_amdgcn_s_setprio(0);                                            \
} while (0)

    for (int kt = 0; kt < NT; kt += 2) {
        GB(kt,     aE, aO, 0);
        GB(kt + 1, aO, aE, 1);
    }
#undef GB

    // epilogue: D col = lane&15, row = (lane>>4)*4 + r
#pragma unroll
    for (int mi = 0; mi < 4; ++mi) {
        long row = (long)by * 128 + wm * 64 + mi * 16 + g * 4;
#pragma unroll
        for (int ni = 0; ni < 4; ++ni) {
            long col = (long)bx * 128 + wn * 64 + ni * 16 + q16;
            f32x4 v = acc[mi][ni];
#pragma unroll
            for (int r = 0; r < 4; ++r)
                cstore(&C[(row + r) * (long)N + col], v[r]);
        }
    }
}

// ---------------------------------------------------------------------------
// Post-gemm1 kernel, R13: Q norm+rope moved into attn (1:1 producer-consumer
// mapping, zero recompute).  Remaining jobs:
//   blocks [0, 2048):       K RMSNorm+RoPE (block = seq pos, 8 K-slots)
//   blocks [2048, 2560):    V transpose
// ---------------------------------------------------------------------------
__global__ __launch_bounds__(256) void post_gemm1_fused(
        const short* __restrict__ qkvb, const int* __restrict__ pos,
        const float* __restrict__ gk,
        short* __restrict__ ko, short* __restrict__ vt)
{
    const int bid = blockIdx.x;

    if (bid < 2048) {
        // ---- K RMSNorm + RoPE: s = bid, slot = NH + (tid>>5) ----
        const int s = bid;
        const int slot = NH + (threadIdx.x >> 5);   // 32..39
        const int p = threadIdx.x & 31, d = p * 4;

        s16x4 xv = *(const s16x4*)(qkvb + (long)s * NQKV + slot * DH + d);
        float x[4];
#pragma unroll
        for (int r = 0; r < 4; ++r) x[r] = bf2f(xv[r]);

        float ss = x[0]*x[0] + x[1]*x[1] + x[2]*x[2] + x[3]*x[3];
#pragma unroll
        for (int o = 1; o < 32; o <<= 1) ss += __shfl_xor(ss, o);
        float rms = rsqrtf(ss * (1.0f / DH) + 1e-6f);

        float y[4];
#pragma unroll
        for (int r = 0; r < 4; ++r) y[r] = x[r] * rms * gk[d + r];

        float y2[4];
#pragma unroll
        for (int r = 0; r < 4; ++r) y2[r] = __shfl_xor(y[r], 16);

        const float po = (float)pos[s];
        const int jbase = d & 63;
        s16x4 ov;
#pragma unroll
        for (int r = 0; r < 4; ++r) {
            float invf = exp2f(-(float)(jbase + r) * (13.287712379549449f / 64.0f));
            float ang = po * invf;
            float c = cosf(ang), sn = sinf(ang);
            float outv = (d < 64) ? (y[r] * c - y2[r] * sn)
                                  : (y[r] * c + y2[r] * sn);
            ov[r] = f2bf(outv);
        }
        *(s16x4*)(ko + ((long)s * NKV + (slot - NH)) * DH + d) = ov;
        return;
    }

    // ---- V transpose: qkvb v-slots -> vt[h][d][s], 64x64 LDS tiles ----
    __shared__ short tile[64][72];
    const int idx2 = bid - 2048;
    const int sb = idx2 & 31, db = (idx2 >> 5) & 1, h = idx2 >> 6;
    const int t = threadIdx.x;
#pragma unroll
    for (int i = 0; i < 2; ++i) {
        int c = i * 256 + t;
        int row = c >> 3, dc = (c & 7) * 8;
        const short* src = qkvb + (long)(sb*64 + row) * NQKV
                           + (NH + NKV + h) * DH + db*64 + dc;
        s16x8 x = *(const s16x8*)src;
#pragma unroll
        for (int jj = 0; jj < 8; ++jj) tile[row][dc + jj] = x[jj];
    }
    __syncthreads();
#pragma unroll
    for (int i = 0; i < 2; ++i) {
        int c = i * 256 + t;
        int dr = c >> 3, sc = (c & 7) * 8;
        s16x8 y;
#pragma unroll
        for (int jj = 0; jj < 8; ++jj) y[jj] = tile[sc + jj][dr];
        short* dst = vt + (long)(h*DH + db*64 + dr) * S_LEN + sb*64 + sc;
        *(s16x8*)dst = y;
    }
}

// ---------------------------------------------------------------------------
// stage one K tile [64][128] and one Vt tile [128][64] into LDS via
// global_load_lds, PRE-SWIZZLED global source (+ linear LDS dest).
// V staging is PREFETCH (fire-and-forget DMA a tile ahead).
// ---------------------------------------------------------------------------
__device__ __forceinline__ void stage_kv(const char* kgB, const char* vgB,
                                         int kt, int t, char* kd, char* vd)
{
    const int w = t >> 6;
#pragma unroll
    for (int ci = 0; ci < 4; ++ci) {
        int c = ci * 256 + t;
        int row = c >> 4, col16 = c & 15;
        const char* gk = kgB + (long)(kt*64 + row) * (NKV*DH*2)
                         + ((col16*16) ^ ((row & 7) << 4));
        gload16(gk, kd + ci*4096 + w*1024);
        int rowv = c >> 3, scol8 = c & 7;
        const char* gv = vgB + (long)rowv * (S_LEN*2) + kt*128
                         + ((scol8*16) ^ ((rowv & 7) << 4));
        gload16(gv, vd + ci*4096 + w*1024);
    }
}

// ---------------------------------------------------------------------------
// Causal GQA flash attention, v12 + R12 (wo-convert tail blocks) + R14
// (Q RMSNorm+RoPE fused, SCRATCH-PROOF: R13's [4][8] float arrays +
// per-element inserts into qf[2][4] spilled 128B/thread to scratch
// [+16MB WRITE_SIZE, VGPR 112, attn 98->135us].  R14: named s16x8 loads,
// immediate bf2f extracts, scalar gq loads, results built in NAMED single
// vectors then whole-vector assigned into qf — R12's proven store pattern.)
// ---------------------------------------------------------------------------
__global__ __launch_bounds__(256, 2) void attn_kernel(
        const float* __restrict__ wo, short* __restrict__ wob,
        const short* __restrict__ qkvb, const int* __restrict__ pos,
        const float* __restrict__ gq,
        const short* __restrict__ kg, const short* __restrict__ vtg,
        short* __restrict__ ctx)
{
    const int bx = blockIdx.x;       // [0,512) attn; [512,2560) wo-convert
    if (bx >= 512) {
        const long n = (long)HID * (NH * DH);
        long i0 = ((long)(bx - 512) * 256 + threadIdx.x) * 4;
        long stride = 2048L * 256 * 4;
        for (long i = i0; i < n; i += stride) {
            float4 v = *(const float4*)(wo + i);
            s16x4 o;
            o[0] = f2bf(v.x); o[1] = f2bf(v.y); o[2] = f2bf(v.z); o[3] = f2bf(v.w);
            *(s16x4*)(wob + i) = o;
        }
        return;
    }

    const int h  = bx & 31;          // head
    const int slot = bx >> 5;        // 0..15
    const int qb = (slot < 8) ? slot : 23 - slot;   // complementary pairing
    const int kvh = h >> 2;          // GQA: rep=4
    const int t = threadIdx.x, w = t >> 6, l = t & 63, g = l >> 4, q16 = l & 15;

    __shared__ char Kl[2][16384];    // [kv64][d128] bf16, swizzled
    __shared__ char Vl[2][16384];    // [d128][kv64] bf16, swizzled
    __shared__ short Pl[4][32 * 64]; // per-wave P[32 q][64 kv], swizzled

    const float scale = 0.08838834764831845f;  // 1/sqrt(128)
    const char* kgB = (const char*)kg + (long)kvh * DH * 2;
    const char* vgB = (const char*)vtg + (long)kvh * DH * (long)S_LEN * 2;

    const int nt = 2 * qb + 2;               // kv-tiles of 64
    int qrow[2];
    qrow[0] = qb*128 + w*32 + q16;
    qrow[1] = qrow[0] + 16;

    // start K/V staging FIRST — Q norm/rope math hides under its latency
    stage_kv(kgB, vgB, 0, t, Kl[0], Vl[0]);

    // ---- R14 fused Q load + RMSNorm + RoPE, scratch-proof codegen ----
    const float rope_c = 13.287712379549449f / 64.0f;
    s16x8 qf[2][4];
#pragma unroll
    for (int s = 0; s < 2; ++s) {
        const short* qptr = qkvb + (long)qrow[s] * NQKV + h * DH;
        s16x8 v0 = *(const s16x8*)(qptr + 0*32 + g*8);
        s16x8 v1 = *(const s16x8*)(qptr + 1*32 + g*8);
        s16x8 v2 = *(const s16x8*)(qptr + 2*32 + g*8);
        s16x8 v3 = *(const s16x8*)(qptr + 3*32 + g*8);
        float ssum = 0.f;
#pragma unroll
        for (int j = 0; j < 8; ++j) {
            float a = bf2f(v0[j]), b = bf2f(v1[j]);
            float c2 = bf2f(v2[j]), d2 = bf2f(v3[j]);
            ssum += a*a + b*b + c2*c2 + d2*d2;
        }
        ssum += __shfl_xor(ssum, 16);
        ssum += __shfl_xor(ssum, 32);
        float rms = rsqrtf(ssum * (1.0f / DH) + 1e-6f);
        float po = (float)pos[qrow[s]];
        s16x8 q0, q1, q2, q3;   // named single vectors: SROA-safe inserts
#pragma unroll
        for (int j = 0; j < 8; ++j) {
            int jb0 = g*8 + j;                 // dk=0 plane, d in [0,32)
            float an0 = po * exp2f(-(float)jb0 * rope_c);
            float co0 = cosf(an0), si0 = sinf(an0);
            float y0 = bf2f(v0[j]) * rms * gq[jb0];
            float y2 = bf2f(v2[j]) * rms * gq[jb0 + 64];
            q0[j] = f2bf(y0 * co0 - y2 * si0);
            q2[j] = f2bf(y2 * co0 + y0 * si0);
            int jb1 = 32 + g*8 + j;            // dk=1 plane, d in [32,64)
            float an1 = po * exp2f(-(float)jb1 * rope_c);
            float co1 = cosf(an1), si1 = sinf(an1);
            float y1 = bf2f(v1[j]) * rms * gq[jb1];
            float y3 = bf2f(v3[j]) * rms * gq[jb1 + 64];
            q1[j] = f2bf(y1 * co1 - y3 * si1);
            q3[j] = f2bf(y3 * co1 + y1 * si1);
        }
        qf[s][0] = q0; qf[s][1] = q1; qf[s][2] = q2; qf[s][3] = q3;
    }

    f32x4 oacc[2][8] = {};
    float m_run[2] = {-1e30f, -1e30f}, l_run[2] = {0.f, 0.f};

    __syncthreads();   // drain vmcnt -> buf0 ready

    for (int kt = 0; kt < nt; ++kt) {
        const int b = kt & 1;
        if (kt + 1 < nt)   // prefetch next tile into other buffer (async)
            stage_kv(kgB, vgB, kt + 1, t, Kl[b ^ 1], Vl[b ^ 1]);
        const char* kb = Kl[b];
        const char* vbb = Vl[b];

        // ---- QK^T swapped: S^T[kv][q] = K * Q^T; K-frags serve both s
        f32x4 sacc[2][4] = {};
        __builtin_amdgcn_s_setprio(1);
#pragma unroll
        for (int m = 0; m < 4; ++m) {
            int kvr = m*16 + q16;
            s16x8 af[4];
#pragma unroll
            for (int dk = 0; dk < 4; ++dk) {
                int byte = (kvr*256 + (dk*32 + g*8)*2) ^ ((kvr & 7) << 4);
                af[dk] = *(const s16x8*)(kb + byte);
            }
#pragma unroll
            for (int s = 0; s < 2; ++s)
#pragma unroll
                for (int dk = 0; dk < 4; ++dk)
                    sacc[s][m] = __builtin_amdgcn_mfma_f32_16x16x32_bf16(
                            af[dk], qf[s][dk], sacc[s][m], 0,0,0);
        }
        __builtin_amdgcn_s_setprio(0);

        // ---- online softmax; lane owns q-columns qrow[0], qrow[1] ----
        const bool diag = (kt >= 2*qb);      // last two tiles straddle diag
        float mx[2];
#pragma unroll
        for (int s = 0; s < 2; ++s) {
            mx[s] = -1e30f;
#pragma unroll
            for (int m = 0; m < 4; ++m)
#pragma unroll
                for (int r = 0; r < 4; ++r) {
                    float x = sacc[s][m][r] * scale;
                    if (diag) {
                        int kv = kt*64 + m*16 + g*4 + r;
                        if (kv > qrow[s]) x = -1e30f;
                    }
                    sacc[s][m][r] = x;
                    mx[s] = fmaxf(mx[s], x);
                }
            mx[s] = fmaxf(mx[s], __shfl_xor(mx[s], 16));
            mx[s] = fmaxf(mx[s], __shfl_xor(mx[s], 32));
        }
        // defer-max: only rescale when max grew by > 8 somewhere (T13)
        if (__any((mx[0] > m_run[0] + 8.f) || (mx[1] > m_run[1] + 8.f))) {
#pragma unroll
            for (int s = 0; s < 2; ++s) {
                float m_new = fmaxf(m_run[s], mx[s]);
                float corr = __expf(m_run[s] - m_new);
                l_run[s] *= corr;
                m_run[s] = m_new;
                float rf[4];
#pragma unroll
                for (int r = 0; r < 4; ++r)
                    rf[r] = __shfl(corr, (g << 4) | (g*4 + r));
#pragma unroll
                for (int nf = 0; nf < 8; ++nf)
#pragma unroll
                    for (int r = 0; r < 4; ++r) oacc[s][nf][r] *= rf[r];
            }
        }
        // exp + pack to bf16 + LDS write (P bounded by e^8 when deferred)
#pragma unroll
        for (int s = 0; s < 2; ++s) {
            float psum = 0.f;
#pragma unroll
            for (int m = 0; m < 4; ++m) {
                s16x4 pk;
#pragma unroll
                for (int r = 0; r < 4; ++r) {
                    float e = __expf(sacc[s][m][r] - m_run[s]);
                    psum += e;
                    pk[r] = f2bf(e);
                }
                int byte = ((s*16 + q16)*128 + (m*16 + g*4)*2) ^ ((q16 & 7) << 4);
                *(s16x4*)((char*)&Pl[w][0] + byte) = pk;
            }
            psum += __shfl_xor(psum, 16);
            psum += __shfl_xor(psum, 32);
            l_run[s] += psum;
        }

        // ---- PV: O[q][d] += P[q][kv] * V[kv][d]; V-frags serve both s
        __builtin_amdgcn_s_setprio(1);
#pragma unroll
        for (int ks = 0; ks < 2; ++ks) {
            s16x8 pa[2];
#pragma unroll
            for (int s = 0; s < 2; ++s) {
                int pbyte = ((s*16 + q16)*128 + (ks*32 + g*8)*2) ^ ((q16 & 7) << 4);
                pa[s] = *(const s16x8*)((const char*)&Pl[w][0] + pbyte);
            }
#pragma unroll
            for (int nf = 0; nf < 8; ++nf) {
                int drow = nf*16 + q16;
                int vbyte = (drow*128 + (ks*32 + g*8)*2) ^ ((drow & 7) << 4);
                s16x8 vbf = *(const s16x8*)(vbb + vbyte);
#pragma unroll
                for (int s = 0; s < 2; ++s)
                    oacc[s][nf] = __builtin_amdgcn_mfma_f32_16x16x32_bf16(
                            pa[s], vbf, oacc[s][nf], 0,0,0);
            }
        }
        __builtin_amdgcn_s_setprio(0);
        __syncthreads();   // tile done; prefetched buffer complete
    }

    // ---- epilogue: divide by l, write ctx[row][h*128 + d] bf16 ----
#pragma unroll
    for (int s = 0; s < 2; ++s) {
        float lr[4];
#pragma unroll
        for (int r = 0; r < 4; ++r)
            lr[r] = __shfl(l_run[s], (g << 4) | (g*4 + r));
#pragma unroll
        for (int nf = 0; nf < 8; ++nf)
#pragma unroll
            for (int r = 0; r < 4; ++r) {
                int row = qb*128 + w*32 + s*16 + g*4 + r;
                int col = h*DH + nf*16 + q16;
                float val = oacc[s][nf][r] / lr[r];
                ctx[(long)row * (NH*DH) + col] = f2bf(val);
            }
    }
}

// ---------------------------------------------------------------------------
// Workspace layout (race-free, peak 111 MB):
//   [0,16)    hsb (gemm1 A, PERMUTED fragment layout, 16MB exactly)
//             -> ctxb (attn out) after gemm1 consumed it
//   [16,67)   wqkvb (gemm1 B, 50.3MB) -> wob (32MB, written during attn
//             launch by trailing convert blocks — wqkvb dead after gemm1)
//   [48,52)   vtbuf (4MB, written after gemm1)
//   [67,91)   qkvb (gemm1 bf16 out, 24MB; attn reads Q from it directly)
//   [107,111) kbuf (4MB)
// ---------------------------------------------------------------------------
extern "C" void kernel_launch(void* const* d_in, const int* in_sizes, int n_in,
                              void* d_out, int out_size, void* d_ws, size_t ws_size,
                              hipStream_t stream)
{
    const int*   positions = (const int*)  d_in[0];
    const float* hs        = (const float*)d_in[1];
    const float* wqkv      = (const float*)d_in[2];
    const float* wo        = (const float*)d_in[3];
    const float* gq        = (const float*)d_in[4];
    const float* gk        = (const float*)d_in[5];
    float* out = (float*)d_out;
    char* ws = (char*)d_ws;

    const size_t MB = 1ull << 20;
    short* hsb   = (short*)(ws);
    short* ctxb  = (short*)(ws);
    short* wqkvb = (short*)(ws + 16*MB);
    short* wob   = (short*)(ws + 16*MB);
    short* vtbuf = (short*)(ws + 48*MB);
    short* qkvb  = (short*)(ws + 67*MB);
    short* kbuf  = (short*)(ws + 107*MB);

    (void)in_sizes; (void)n_in; (void)out_size; (void)ws_size;

    convert_hs_wqkv<<<2048, 256, 0, stream>>>(hs, hsb, wqkv, wqkvb);
    gemm192<short><<<dim3(NQKV/192, S_LEN/128), 256, 0, stream>>>(
            hsb, wqkvb, qkvb, S_LEN, NQKV, HID);
    post_gemm1_fused<<<2560, 256, 0, stream>>>(
            qkvb, positions, gk, kbuf, vtbuf);
    attn_kernel<<<dim3(2560), 256, 0, stream>>>(
            wo, wob, qkvb, positions, gq, kbuf, vtbuf, ctxb);
    gemm_bt<float><<<dim3(HID/128, S_LEN/128), 256, 0, stream>>>(
            ctxb, wob, out, S_LEN, HID, HID);
}

// Round 15
// 286.377 us; speedup vs baseline: 1.1006x; 1.0996x over previous
//
#include <hip/hip_runtime.h>
#include <hip/hip_bf16.h>

// Problem constants
#define S_LEN 2048
#define HID   4096
#define NH    32
#define NKV   8
#define DH    128
#define NQKV  ((NH + 2*NKV) * DH)   // 6144

typedef __attribute__((ext_vector_type(8))) short s16x8;
typedef __attribute__((ext_vector_type(4))) short s16x4;
typedef __attribute__((ext_vector_type(4))) float f32x4;

__device__ __forceinline__ short f2bf(float x) {
    union { __hip_bfloat16 b; short s; } u;
    u.b = __float2bfloat16(x);
    return u.s;
}
__device__ __forceinline__ float bf2f(short s) {
    union { unsigned int u; float f; } v;
    v.u = ((unsigned int)(unsigned short)s) << 16;
    return v.f;
}

// async global->LDS, 16B per lane; lds dest = wave-uniform base + lane*16
__device__ __forceinline__ void gload16(const void* g, void* l) {
    __builtin_amdgcn_global_load_lds(
        (const __attribute__((address_space(1))) void*)g,
        (__attribute__((address_space(3))) void*)l,
        16, 0, 0);
}

__device__ __forceinline__ void cstore(float* p, float v) { *p = v; }
__device__ __forceinline__ void cstore(short* p, float v) { *p = f2bf(v); }

#define ROPE_C (13.287712379549449f / 64.0f)

// ---------------------------------------------------------------------------
// conversion kernel (R8-measured) + R15 rope table.
// blocks [0,1536): wqkv f32->bf16 LINEAR (gemm1 B).
// blocks [1536,2048): hs f32->bf16 PERMUTED into MFMA A-fragment order.
// blocks [2048,2112): cos/sin table cst[s][j<64] (float2, 1MB) — R14 post-
// mortem: recomputing trig in attn's prologue (64 cos/sin per lane, 1/16
// the parallelism of post) cost +35us; table is built ONCE here at full
// parallelism with the bit-identical expression.
// ---------------------------------------------------------------------------
__global__ __launch_bounds__(256) void convert_hs_wqkv(
        const float* __restrict__ hs, short* __restrict__ hsp,
        const float* __restrict__ wq, short* __restrict__ wqb,
        const int* __restrict__ pos, float* __restrict__ cst)
{
    const int bid = blockIdx.x;
    if (bid < 1536) {
        const long n = (long)NQKV * HID;
        long i0 = ((long)bid * 256 + threadIdx.x) * 4;
        long stride = 1536L * 256 * 4;
        for (long i = i0; i < n; i += stride) {
            float4 v = *(const float4*)(wq + i);
            s16x4 o;
            o[0] = f2bf(v.x); o[1] = f2bf(v.y); o[2] = f2bf(v.z); o[3] = f2bf(v.w);
            *(s16x4*)(wqb + i) = o;
        }
        return;
    }
    if (bid < 2048) {
        // hs permute: 1M 16B-chunks; c = (m16*128 + k32)*64 + lane
        const int nchunk = (S_LEN / 16) * (HID / 32) * 64;   // 1,048,576
        for (int c = (bid - 1536) * 256 + threadIdx.x; c < nchunk; c += 512 * 256) {
            int lane = c & 63, k32 = (c >> 6) & 127, m16 = c >> 13;
            int row = m16 * 16 + (lane & 15);
            int k   = k32 * 32 + (lane >> 4) * 8;
            const float4* p = (const float4*)(hs + (long)row * HID + k);
            float4 v0 = p[0], v1 = p[1];
            s16x8 o;
            o[0] = f2bf(v0.x); o[1] = f2bf(v0.y); o[2] = f2bf(v0.z); o[3] = f2bf(v0.w);
            o[4] = f2bf(v1.x); o[5] = f2bf(v1.y); o[6] = f2bf(v1.z); o[7] = f2bf(v1.w);
            *(s16x8*)(hsp + (long)c * 8) = o;
        }
        return;
    }
    // rope table: idx in [0,16384); s = idx>>3, j = (idx&7)*8 .. +7
    const int idx = (bid - 2048) * 256 + threadIdx.x;
    const int s = idx >> 3, j0 = (idx & 7) * 8;
    const float po = (float)pos[s];
#pragma unroll
    for (int jj = 0; jj < 8; ++jj) {
        int j = j0 + jj;
        float ang = po * exp2f(-(float)j * ROPE_C);
        float2 cs;
        cs.x = cosf(ang);
        cs.y = sinf(ang);
        *(float2*)(cst + ((long)s * 64 + j) * 2) = cs;
    }
}

// ---------------------------------------------------------------------------
// gemm1 (R7/R11-measured, 98.5us, MfmaUtil 45.9 — best gemm192 variant):
// 128x192-tile bf16 GEMM, C = A * B^T.  A read DIRECTLY from global in
// fragment layout (hsp) — LDS holds B only (2 x 24KB).  One barrier/tile.
// NOTE (R1-R10): seven structural variants all pinned at MfmaUtil 44-46%
// — plateau is structural for this tile family; gemm1 closed.
// ---------------------------------------------------------------------------
template <typename OT>
__global__ __launch_bounds__(256, 2) void gemm192(
        const short* __restrict__ Ap, const short* __restrict__ B,
        OT* __restrict__ C, int M, int N, int K)
{
    __shared__ char lds[49152];   // B only: 2 slots x 24KB
    const int t = threadIdx.x;
    const int w = t >> 6, l = t & 63, g = l >> 4, q16 = l & 15;
    const int wm = w >> 1, wn = w & 1;       // wave grid 2(M) x 2(N)
    const int bx = blockIdx.x, by = blockIdx.y;
    const int NT = K >> 6;                   // 64 at K=4096 (even)

    // B staging global byte offsets (chunk pre-swizzled)
    const int srow = t >> 3;
    const int schunk = (t & 7) ^ (srow & 7);
    unsigned goffB[6];
#pragma unroll
    for (int i = 0; i < 6; ++i)
        goffB[i] = (unsigned)(((bx * 192 + i * 32 + srow) * K) * 2 + schunk * 16);
    const int dstw = w * 1024;

    auto STAGE = [&](int kt) {               // 6 DMA: B 24KB
        char* dB = lds + (kt & 1) * 24576 + dstw;
        const unsigned kb = (unsigned)kt * 128;
#pragma unroll
        for (int i = 0; i < 6; ++i)
            gload16((const char*)B + (goffB[i] + kb), dB + i * 4096);
    };

    // A fragment global byte bases: ((m16*128 + k32)*64 + l)*16
    unsigned aBase[4];
#pragma unroll
    for (int mi = 0; mi < 4; ++mi)
        aBase[mi] = ((unsigned)((by * 8 + wm * 4 + mi) * 128) * 64 + (unsigned)l) * 16;

    // B LDS read offsets (row&7 == q16&7)
    int boff[6];
#pragma unroll
    for (int ni = 0; ni < 6; ++ni) boff[ni] = (wn * 96 + ni * 16 + q16) * 128;
    const int sw0 = ((g) ^ (q16 & 7)) << 4;
    const int sw1 = ((4 + g) ^ (q16 & 7)) << 4;

    f32x4 acc[4][6] = {};
    s16x8 aE[4][2], aO[4][2], b0E[2][2], b0O[2][2], b1[4][2];

    // prologue: STAGE(0) -> A(0) loads -> STAGE(1); vmcnt(6) drains
    // STAGE(0)+A(0), keeps STAGE(1) flying; barrier publishes B(0).
    STAGE(0);
    __builtin_amdgcn_sched_barrier(0);
#pragma unroll
    for (int mi = 0; mi < 4; ++mi)
#pragma unroll
        for (int kk = 0; kk < 2; ++kk)
            aE[mi][kk] = *(const s16x8*)((const char*)Ap + aBase[mi] + kk * 1024);
    __builtin_amdgcn_sched_barrier(0);
    STAGE(1);
    asm volatile("s_waitcnt vmcnt(6)" ::: "memory");
    __builtin_amdgcn_s_barrier();
    {
        const char* B0 = lds;
#pragma unroll
        for (int ni = 0; ni < 2; ++ni) {
            b0E[ni][0] = *(const s16x8*)(B0 + boff[ni] + sw0);
            b0E[ni][1] = *(const s16x8*)(B0 + boff[ni] + sw1);
        }
        asm volatile("s_waitcnt lgkmcnt(0)" ::: "memory");
        __builtin_amdgcn_sched_barrier(0);
    }

#define GB(KT, AC, AN, B0C, B0N, PAR) do {                                    \
    /* 1. b1(t) ds_reads; M0 on pre-loaded regs (zero wait) */                \
    const char* Bc_ = lds + (PAR) * 24576;                                    \
    _Pragma("unroll")                                                         \
    for (int ni = 0; ni < 4; ++ni) {                                          \
        b1[ni][0] = *(const s16x8*)(Bc_ + boff[2 + ni] + sw0);                \
        b1[ni][1] = *(const s16x8*)(Bc_ + boff[2 + ni] + sw1);                \
    }                                                                         \
    __builtin_amdgcn_sched_barrier(0);                                        \
    __builtin_amdgcn_s_setprio(1);                                            \
    _Pragma("unroll")                                                         \
    for (int mi = 0; mi < 4; ++mi)                                            \
    _Pragma("unroll")                                                         \
    for (int ni = 0; ni < 2; ++ni)                                            \
    _Pragma("unroll")                                                         \
    for (int kk = 0; kk < 2; ++kk)                                            \
        acc[mi][ni] = __builtin_amdgcn_mfma_f32_16x16x32_bf16(                \
                AC[mi][kk], B0C[ni][kk], acc[mi][ni], 0, 0, 0);               \
    __builtin_amdgcn_s_setprio(0);                                            \
    /* 2. gates + the ONE barrier: slot t free, B(t+1) published */           \
    asm volatile("s_waitcnt lgkmcnt(0)" ::: "memory");                        \
    __builtin_amdgcn_sched_barrier(0);                                        \
    asm volatile("s_waitcnt vmcnt(0)" ::: "memory");                          \
    __builtin_amdgcn_s_barrier();                                             \
    /* 3. A(t+1) frag loads FIRST, then STAGE(t+2), then b0(t+1) reads */     \
    if ((KT) + 1 < NT) {                                                      \
        _Pragma("unroll")                                                     \
        for (int mi = 0; mi < 4; ++mi)                                        \
        _Pragma("unroll")                                                     \
        for (int kk = 0; kk < 2; ++kk)                                        \
            AN[mi][kk] = *(const s16x8*)((const char*)Ap + aBase[mi]          \
                    + (((KT) + 1) * 2 + kk) * 1024);                          \
    }                                                                         \
    __builtin_amdgcn_sched_barrier(0);                                        \
    if ((KT) + 2 < NT) STAGE((KT) + 2);                                       \
    if ((KT) + 1 < NT) {                                                      \
        const char* Bn_ = lds + ((PAR) ^ 1) * 24576;                          \
        _Pragma("unroll")                                                     \
        for (int ni = 0; ni < 2; ++ni) {                                      \
            B0N[ni][0] = *(const s16x8*)(Bn_ + boff[ni] + sw0);               \
            B0N[ni][1] = *(const s16x8*)(Bn_ + boff[ni] + sw1);               \
        }                                                                     \
    }                                                                         \
    __builtin_amdgcn_sched_barrier(0);                                        \
    /* 4. M1 covers step-3 latency */                                         \
    __builtin_amdgcn_s_setprio(1);                                            \
    _Pragma("unroll")                                                         \
    for (int mi = 0; mi < 4; ++mi)                                            \
    _Pragma("unroll")                                                         \
    for (int ni = 0; ni < 4; ++ni)                                            \
    _Pragma("unroll")                                                         \
    for (int kk = 0; kk < 2; ++kk)                                            \
        acc[mi][2 + ni] = __builtin_amdgcn_mfma_f32_16x16x32_bf16(            \
                AC[mi][kk], b1[ni][kk], acc[mi][2 + ni], 0, 0, 0);            \
    __builtin_amdgcn_s_setprio(0);                                            \
    /* 5. end gates: b0(t+1) in regs; A(t+1) drained, STAGE(t+2) flies */     \
    asm volatile("s_waitcnt lgkmcnt(0)" ::: "memory");                        \
    __builtin_amdgcn_sched_barrier(0);                                        \
    if ((KT) + 2 < NT) asm volatile("s_waitcnt vmcnt(6)" ::: "memory");       \
    else               asm volatile("s_waitcnt vmcnt(0)" ::: "memory");       \
    __builtin_amdgcn_sched_barrier(0);                                        \
} while (0)

    for (int kt = 0; kt < NT; kt += 2) {
        GB(kt,     aE, aO, b0E, b0O, 0);
        GB(kt + 1, aO, aE, b0O, b0E, 1);
    }
#undef GB

    // epilogue: D col = lane&15, row = (lane>>4)*4 + r
#pragma unroll
    for (int mi = 0; mi < 4; ++mi) {
        long row = (long)by * 128 + wm * 64 + mi * 16 + g * 4;
#pragma unroll
        for (int ni = 0; ni < 6; ++ni) {
            long col = (long)bx * 192 + wn * 96 + ni * 16 + q16;
            f32x4 v = acc[mi][ni];
#pragma unroll
            for (int r = 0; r < 4; ++r)
                cstore(&C[(row + r) * (long)N + col], v[r]);
        }
    }
}

// ---------------------------------------------------------------------------
// gemm2: bf16 GEMM, C[M][N] = A[M][K] * B[N][K]^T.  R5 state (kept): 128x128
// tile, 256 threads (4 waves, 2Mx2N, 64x64/wave), counted lgkmcnt(4) gate,
// A-frag readahead dbuf, one barrier per K-tile, 2 blocks/CU.
// ---------------------------------------------------------------------------
template <typename OT>
__global__ __launch_bounds__(256, 2) void gemm_bt(
        const short* __restrict__ A, const short* __restrict__ B,
        OT* __restrict__ C, int M, int N, int K)
{
    __shared__ char lds[65536];   // A: 2 x 16KB at [0,32K); B: 2 x 16KB at [32K,64K)
    const int t = threadIdx.x;
    const int w = t >> 6, l = t & 63, g = l >> 4, q16 = l & 15;
    const int wm = w >> 1, wn = w & 1;       // wave grid 2(M) x 2(N)
    const int bx = blockIdx.x, by = blockIdx.y;
    const int NT = K >> 6;                   // 64 at K=4096 (even)

    // staging global byte offsets (chunk pre-swizzled)
    const int srow = t >> 3;                 // 0..31 within a 32-row band
    const int schunk = (t & 7) ^ (srow & 7);
    unsigned goffA[4], goffB[4];
#pragma unroll
    for (int i = 0; i < 4; ++i) {
        goffA[i] = (unsigned)(((by * 128 + i * 32 + srow) * K) * 2 + schunk * 16);
        goffB[i] = (unsigned)(((bx * 128 + i * 32 + srow) * K) * 2 + schunk * 16);
    }
    const int dstw = w * 1024;               // wave-uniform dest base part

    auto STAGE = [&](int kt) {               // 8 DMA instrs: A 16KB + B 16KB
        const int par = kt & 1;
        char* dA = lds + par * 16384 + dstw;
        char* dB = lds + 32768 + par * 16384 + dstw;
        const unsigned kb = (unsigned)kt * 128;
#pragma unroll
        for (int i = 0; i < 4; ++i) {
            gload16((const char*)A + (goffA[i] + kb), dA + i * 4096);
            gload16((const char*)B + (goffB[i] + kb), dB + i * 4096);
        }
    };

    // LDS read offsets (row&7 == q16&7 everywhere)
    int aoff[4], boff[4];
#pragma unroll
    for (int i = 0; i < 4; ++i) {
        aoff[i] = (wm * 64 + i * 16 + q16) * 128;
        boff[i] = (wn * 64 + i * 16 + q16) * 128;
    }
    const int sw0 = ((g) ^ (q16 & 7)) << 4;
    const int sw1 = ((4 + g) ^ (q16 & 7)) << 4;

    f32x4 acc[4][4] = {};
    s16x8 aE[4][2], aO[4][2], bf[4][2];

    // prologue: stage tiles 0,1; publish tile0; read-ahead A(0) -> aE
    STAGE(0); STAGE(1);
    asm volatile("s_waitcnt vmcnt(8)" ::: "memory");
    __builtin_amdgcn_s_barrier();
    {
        const char* A0 = lds;
#pragma unroll
        for (int mi = 0; mi < 4; ++mi) {
            aE[mi][0] = *(const s16x8*)(A0 + aoff[mi] + sw0);
            aE[mi][1] = *(const s16x8*)(A0 + aoff[mi] + sw1);
        }
    }

#define GB(KT, AC, AN, PAR) do {                                              \
    const char* Bs_ = lds + 32768 + (PAR) * 16384;                            \
    _Pragma("unroll")                                                         \
    for (int ni = 0; ni < 4; ++ni) {                                          \
        bf[ni][0] = *(const s16x8*)(Bs_ + boff[ni] + sw0);                    \
        bf[ni][1] = *(const s16x8*)(Bs_ + boff[ni] + sw1);                    \
    }                                                                         \
    asm volatile("s_waitcnt lgkmcnt(4)" ::: "memory");  /* A + b01 done */    \
    __builtin_amdgcn_sched_barrier(0);                                        \
    __builtin_amdgcn_s_setprio(1);                                            \
    _Pragma("unroll")                                                         \
    for (int mi = 0; mi < 4; ++mi)                                            \
    _Pragma("unroll")                                                         \
    for (int ni = 0; ni < 2; ++ni)                                            \
    _Pragma("unroll")                                                         \
    for (int kk = 0; kk < 2; ++kk)                                            \
        acc[mi][ni] = __builtin_amdgcn_mfma_f32_16x16x32_bf16(                \
                AC[mi][kk], bf[ni][kk], acc[mi][ni], 0, 0, 0);                \
    __builtin_amdgcn_s_setprio(0);                                            \
    asm volatile("s_waitcnt lgkmcnt(0)" ::: "memory");  /* b23 done */        \
    __builtin_amdgcn_sched_barrier(0);                                        \
    asm volatile("s_waitcnt vmcnt(0)" ::: "memory");    /* t+1 resident */    \
    __builtin_amdgcn_s_barrier();   /* slot t free + tile t+1 published */    \
    if ((KT) + 2 < NT) STAGE((KT) + 2);                                       \
    if ((KT) + 1 < NT) {            /* read-ahead A(t+1) under M1 */          \
        const char* An_ = lds + (((PAR) ^ 1) * 16384);                        \
        _Pragma("unroll")                                                     \
        for (int mi = 0; mi < 4; ++mi) {                                      \
            AN[mi][0] = *(const s16x8*)(An_ + aoff[mi] + sw0);                \
            AN[mi][1] = *(const s16x8*)(An_ + aoff[mi] + sw1);                \
        }                                                                     \
    }                                                                         \
    __builtin_amdgcn_s_setprio(1);                                            \
    _Pragma("unroll")                                                         \
    for (int mi = 0; mi < 4; ++mi)                                            \
    _Pragma("unroll")                                                         \
    for (int ni = 0; ni < 2; ++ni)                                            \
    _Pragma("unroll")                                                         \
    for (int kk = 0; kk < 2; ++kk)                                            \
        acc[mi][2 + ni] = __builtin_amdgcn_mfma_f32_16x16x32_bf16(            \
                AC[mi][kk], bf[2 + ni][kk], acc[mi][2 + ni], 0, 0, 0);        \
    __builtin_amdgcn_s_setprio(0);                                            \
} while (0)

    for (int kt = 0; kt < NT; kt += 2) {
        GB(kt,     aE, aO, 0);
        GB(kt + 1, aO, aE, 1);
    }
#undef GB

    // epilogue: D col = lane&15, row = (lane>>4)*4 + r
#pragma unroll
    for (int mi = 0; mi < 4; ++mi) {
        long row = (long)by * 128 + wm * 64 + mi * 16 + g * 4;
#pragma unroll
        for (int ni = 0; ni < 4; ++ni) {
            long col = (long)bx * 128 + wn * 64 + ni * 16 + q16;
            f32x4 v = acc[mi][ni];
#pragma unroll
            for (int r = 0; r < 4; ++r)
                cstore(&C[(row + r) * (long)N + col], v[r]);
        }
    }
}

// ---------------------------------------------------------------------------
// Post-gemm1 kernel, R13/R15: Q norm+rope lives in attn; K-norm uses the
// rope TABLE (no trig).  Jobs:
//   blocks [0, 2048):       K RMSNorm+RoPE (block = seq pos, 8 K-slots)
//   blocks [2048, 2560):    V transpose
// ---------------------------------------------------------------------------
__global__ __launch_bounds__(256) void post_gemm1_fused(
        const short* __restrict__ qkvb, const float* __restrict__ cst,
        const float* __restrict__ gk,
        short* __restrict__ ko, short* __restrict__ vt)
{
    const int bid = blockIdx.x;

    if (bid < 2048) {
        // ---- K RMSNorm + RoPE: s = bid, slot = NH + (tid>>5) ----
        const int s = bid;
        const int slot = NH + (threadIdx.x >> 5);   // 32..39
        const int p = threadIdx.x & 31, d = p * 4;

        s16x4 xv = *(const s16x4*)(qkvb + (long)s * NQKV + slot * DH + d);
        float x[4];
#pragma unroll
        for (int r = 0; r < 4; ++r) x[r] = bf2f(xv[r]);

        float ss = x[0]*x[0] + x[1]*x[1] + x[2]*x[2] + x[3]*x[3];
#pragma unroll
        for (int o = 1; o < 32; o <<= 1) ss += __shfl_xor(ss, o);
        float rms = rsqrtf(ss * (1.0f / DH) + 1e-6f);

        float y[4];
#pragma unroll
        for (int r = 0; r < 4; ++r) y[r] = x[r] * rms * gk[d + r];

        float y2[4];
#pragma unroll
        for (int r = 0; r < 4; ++r) y2[r] = __shfl_xor(y[r], 16);

        const int jbase = d & 63;
        s16x4 ov;
#pragma unroll
        for (int r = 0; r < 4; ++r) {
            float2 cs = *(const float2*)(cst + ((long)s * 64 + jbase + r) * 2);
            float outv = (d < 64) ? (y[r] * cs.x - y2[r] * cs.y)
                                  : (y[r] * cs.x + y2[r] * cs.y);
            ov[r] = f2bf(outv);
        }
        *(s16x4*)(ko + ((long)s * NKV + (slot - NH)) * DH + d) = ov;
        return;
    }

    // ---- V transpose: qkvb v-slots -> vt[h][d][s], 64x64 LDS tiles ----
    __shared__ short tile[64][72];
    const int idx2 = bid - 2048;
    const int sb = idx2 & 31, db = (idx2 >> 5) & 1, h = idx2 >> 6;
    const int t = threadIdx.x;
#pragma unroll
    for (int i = 0; i < 2; ++i) {
        int c = i * 256 + t;
        int row = c >> 3, dc = (c & 7) * 8;
        const short* src = qkvb + (long)(sb*64 + row) * NQKV
                           + (NH + NKV + h) * DH + db*64 + dc;
        s16x8 x = *(const s16x8*)src;
#pragma unroll
        for (int jj = 0; jj < 8; ++jj) tile[row][dc + jj] = x[jj];
    }
    __syncthreads();
#pragma unroll
    for (int i = 0; i < 2; ++i) {
        int c = i * 256 + t;
        int dr = c >> 3, sc = (c & 7) * 8;
        s16x8 y;
#pragma unroll
        for (int jj = 0; jj < 8; ++jj) y[jj] = tile[sc + jj][dr];
        short* dst = vt + (long)(h*DH + db*64 + dr) * S_LEN + sb*64 + sc;
        *(s16x8*)dst = y;
    }
}

// ---------------------------------------------------------------------------
// stage one K tile [64][128] and one Vt tile [128][64] into LDS via
// global_load_lds, PRE-SWIZZLED global source (+ linear LDS dest).
// V staging is PREFETCH (fire-and-forget DMA a tile ahead).
// ---------------------------------------------------------------------------
__device__ __forceinline__ void stage_kv(const char* kgB, const char* vgB,
                                         int kt, int t, char* kd, char* vd)
{
    const int w = t >> 6;
#pragma unroll
    for (int ci = 0; ci < 4; ++ci) {
        int c = ci * 256 + t;
        int row = c >> 4, col16 = c & 15;
        const char* gk = kgB + (long)(kt*64 + row) * (NKV*DH*2)
                         + ((col16*16) ^ ((row & 7) << 4));
        gload16(gk, kd + ci*4096 + w*1024);
        int rowv = c >> 3, scol8 = c & 7;
        const char* gv = vgB + (long)rowv * (S_LEN*2) + kt*128
                         + ((scol8*16) ^ ((rowv & 7) << 4));
        gload16(gv, vd + ci*4096 + w*1024);
    }
}

// ---------------------------------------------------------------------------
// Causal GQA flash attention, v12 + R12 (wo-convert tail blocks) + R15
// (Q RMSNorm+RoPE fused with TABLE-based rope — R13/R14's in-prologue
// cosf/sinf [64/lane at 1/16 parallelism] cost +35us; the table turns the
// prologue into loads + FMA).
// ---------------------------------------------------------------------------
__global__ __launch_bounds__(256, 2) void attn_kernel(
        const float* __restrict__ wo, short* __restrict__ wob,
        const short* __restrict__ qkvb, const float* __restrict__ cst,
        const float* __restrict__ gq,
        const short* __restrict__ kg, const short* __restrict__ vtg,
        short* __restrict__ ctx)
{
    const int bx = blockIdx.x;       // [0,512) attn; [512,2560) wo-convert
    if (bx >= 512) {
        const long n = (long)HID * (NH * DH);
        long i0 = ((long)(bx - 512) * 256 + threadIdx.x) * 4;
        long stride = 2048L * 256 * 4;
        for (long i = i0; i < n; i += stride) {
            float4 v = *(const float4*)(wo + i);
            s16x4 o;
            o[0] = f2bf(v.x); o[1] = f2bf(v.y); o[2] = f2bf(v.z); o[3] = f2bf(v.w);
            *(s16x4*)(wob + i) = o;
        }
        return;
    }

    const int h  = bx & 31;          // head
    const int slot = bx >> 5;        // 0..15
    const int qb = (slot < 8) ? slot : 23 - slot;   // complementary pairing
    const int kvh = h >> 2;          // GQA: rep=4
    const int t = threadIdx.x, w = t >> 6, l = t & 63, g = l >> 4, q16 = l & 15;

    __shared__ char Kl[2][16384];    // [kv64][d128] bf16, swizzled
    __shared__ char Vl[2][16384];    // [d128][kv64] bf16, swizzled
    __shared__ short Pl[4][32 * 64]; // per-wave P[32 q][64 kv], swizzled

    const float scale = 0.08838834764831845f;  // 1/sqrt(128)
    const char* kgB = (const char*)kg + (long)kvh * DH * 2;
    const char* vgB = (const char*)vtg + (long)kvh * DH * (long)S_LEN * 2;

    const int nt = 2 * qb + 2;               // kv-tiles of 64
    int qrow[2];
    qrow[0] = qb*128 + w*32 + q16;
    qrow[1] = qrow[0] + 16;

    // start K/V staging FIRST — Q norm/rope hides under its latency
    stage_kv(kgB, vgB, 0, t, Kl[0], Vl[0]);

    // ---- R15 fused Q load + RMSNorm + table-RoPE (loads + FMA only) ----
    s16x8 qf[2][4];
#pragma unroll
    for (int s = 0; s < 2; ++s) {
        const short* qptr = qkvb + (long)qrow[s] * NQKV + h * DH;
        s16x8 v0 = *(const s16x8*)(qptr + 0*32 + g*8);
        s16x8 v1 = *(const s16x8*)(qptr + 1*32 + g*8);
        s16x8 v2 = *(const s16x8*)(qptr + 2*32 + g*8);
        s16x8 v3 = *(const s16x8*)(qptr + 3*32 + g*8);
        float ssum = 0.f;
#pragma unroll
        for (int j = 0; j < 8; ++j) {
            float a = bf2f(v0[j]), b = bf2f(v1[j]);
            float c2 = bf2f(v2[j]), d2 = bf2f(v3[j]);
            ssum += a*a + b*b + c2*c2 + d2*d2;
        }
        ssum += __shfl_xor(ssum, 16);
        ssum += __shfl_xor(ssum, 32);
        float rms = rsqrtf(ssum * (1.0f / DH) + 1e-6f);
        const float* csp = cst + (long)qrow[s] * 128;   // float2 cst[..][64]
        s16x8 q0, q1, q2, q3;   // named single vectors: SROA-safe inserts
#pragma unroll
        for (int j = 0; j < 8; ++j) {
            int jb0 = g*8 + j;                 // dk=0 plane, d in [0,32)
            float2 cs0 = *(const float2*)(csp + jb0 * 2);
            float y0 = bf2f(v0[j]) * rms * gq[jb0];
            float y2 = bf2f(v2[j]) * rms * gq[jb0 + 64];
            q0[j] = f2bf(y0 * cs0.x - y2 * cs0.y);
            q2[j] = f2bf(y2 * cs0.x + y0 * cs0.y);
            int jb1 = 32 + g*8 + j;            // dk=1 plane, d in [32,64)
            float2 cs1 = *(const float2*)(csp + jb1 * 2);
            float y1 = bf2f(v1[j]) * rms * gq[jb1];
            float y3 = bf2f(v3[j]) * rms * gq[jb1 + 64];
            q1[j] = f2bf(y1 * cs1.x - y3 * cs1.y);
            q3[j] = f2bf(y3 * cs1.x + y1 * cs1.y);
        }
        qf[s][0] = q0; qf[s][1] = q1; qf[s][2] = q2; qf[s][3] = q3;
    }

    f32x4 oacc[2][8] = {};
    float m_run[2] = {-1e30f, -1e30f}, l_run[2] = {0.f, 0.f};

    __syncthreads();   // drain vmcnt -> buf0 ready

    for (int kt = 0; kt < nt; ++kt) {
        const int b = kt & 1;
        if (kt + 1 < nt)   // prefetch next tile into other buffer (async)
            stage_kv(kgB, vgB, kt + 1, t, Kl[b ^ 1], Vl[b ^ 1]);
        const char* kb = Kl[b];
        const char* vbb = Vl[b];

        // ---- QK^T swapped: S^T[kv][q] = K * Q^T; K-frags serve both s
        f32x4 sacc[2][4] = {};
        __builtin_amdgcn_s_setprio(1);
#pragma unroll
        for (int m = 0; m < 4; ++m) {
            int kvr = m*16 + q16;
            s16x8 af[4];
#pragma unroll
            for (int dk = 0; dk < 4; ++dk) {
                int byte = (kvr*256 + (dk*32 + g*8)*2) ^ ((kvr & 7) << 4);
                af[dk] = *(const s16x8*)(kb + byte);
            }
#pragma unroll
            for (int s = 0; s < 2; ++s)
#pragma unroll
                for (int dk = 0; dk < 4; ++dk)
                    sacc[s][m] = __builtin_amdgcn_mfma_f32_16x16x32_bf16(
                            af[dk], qf[s][dk], sacc[s][m], 0,0,0);
        }
        __builtin_amdgcn_s_setprio(0);

        // ---- online softmax; lane owns q-columns qrow[0], qrow[1] ----
        const bool diag = (kt >= 2*qb);      // last two tiles straddle diag
        float mx[2];
#pragma unroll
        for (int s = 0; s < 2; ++s) {
            mx[s] = -1e30f;
#pragma unroll
            for (int m = 0; m < 4; ++m)
#pragma unroll
                for (int r = 0; r < 4; ++r) {
                    float x = sacc[s][m][r] * scale;
                    if (diag) {
                        int kv = kt*64 + m*16 + g*4 + r;
                        if (kv > qrow[s]) x = -1e30f;
                    }
                    sacc[s][m][r] = x;
                    mx[s] = fmaxf(mx[s], x);
                }
            mx[s] = fmaxf(mx[s], __shfl_xor(mx[s], 16));
            mx[s] = fmaxf(mx[s], __shfl_xor(mx[s], 32));
        }
        // defer-max: only rescale when max grew by > 8 somewhere (T13)
        if (__any((mx[0] > m_run[0] + 8.f) || (mx[1] > m_run[1] + 8.f))) {
#pragma unroll
            for (int s = 0; s < 2; ++s) {
                float m_new = fmaxf(m_run[s], mx[s]);
                float corr = __expf(m_run[s] - m_new);
                l_run[s] *= corr;
                m_run[s] = m_new;
                float rf[4];
#pragma unroll
                for (int r = 0; r < 4; ++r)
                    rf[r] = __shfl(corr, (g << 4) | (g*4 + r));
#pragma unroll
                for (int nf = 0; nf < 8; ++nf)
#pragma unroll
                    for (int r = 0; r < 4; ++r) oacc[s][nf][r] *= rf[r];
            }
        }
        // exp + pack to bf16 + LDS write (P bounded by e^8 when deferred)
#pragma unroll
        for (int s = 0; s < 2; ++s) {
            float psum = 0.f;
#pragma unroll
            for (int m = 0; m < 4; ++m) {
                s16x4 pk;
#pragma unroll
                for (int r = 0; r < 4; ++r) {
                    float e = __expf(sacc[s][m][r] - m_run[s]);
                    psum += e;
                    pk[r] = f2bf(e);
                }
                int byte = ((s*16 + q16)*128 + (m*16 + g*4)*2) ^ ((q16 & 7) << 4);
                *(s16x4*)((char*)&Pl[w][0] + byte) = pk;
            }
            psum += __shfl_xor(psum, 16);
            psum += __shfl_xor(psum, 32);
            l_run[s] += psum;
        }

        // ---- PV: O[q][d] += P[q][kv] * V[kv][d]; V-frags serve both s
        __builtin_amdgcn_s_setprio(1);
#pragma unroll
        for (int ks = 0; ks < 2; ++ks) {
            s16x8 pa[2];
#pragma unroll
            for (int s = 0; s < 2; ++s) {
                int pbyte = ((s*16 + q16)*128 + (ks*32 + g*8)*2) ^ ((q16 & 7) << 4);
                pa[s] = *(const s16x8*)((const char*)&Pl[w][0] + pbyte);
            }
#pragma unroll
            for (int nf = 0; nf < 8; ++nf) {
                int drow = nf*16 + q16;
                int vbyte = (drow*128 + (ks*32 + g*8)*2) ^ ((drow & 7) << 4);
                s16x8 vbf = *(const s16x8*)(vbb + vbyte);
#pragma unroll
                for (int s = 0; s < 2; ++s)
                    oacc[s][nf] = __builtin_amdgcn_mfma_f32_16x16x32_bf16(
                            pa[s], vbf, oacc[s][nf], 0,0,0);
            }
        }
        __builtin_amdgcn_s_setprio(0);
        __syncthreads();   // tile done; prefetched buffer complete
    }

    // ---- epilogue: divide by l, write ctx[row][h*128 + d] bf16 ----
#pragma unroll
    for (int s = 0; s < 2; ++s) {
        float lr[4];
#pragma unroll
        for (int r = 0; r < 4; ++r)
            lr[r] = __shfl(l_run[s], (g << 4) | (g*4 + r));
#pragma unroll
        for (int nf = 0; nf < 8; ++nf)
#pragma unroll
            for (int r = 0; r < 4; ++r) {
                int row = qb*128 + w*32 + s*16 + g*4 + r;
                int col = h*DH + nf*16 + q16;
                float val = oacc[s][nf][r] / lr[r];
                ctx[(long)row * (NH*DH) + col] = f2bf(val);
            }
    }
}

// ---------------------------------------------------------------------------
// Workspace layout (race-free, peak 111 MB):
//   [0,16)    hsb (gemm1 A, PERMUTED fragment layout, 16MB exactly)
//             -> ctxb (attn out) after gemm1 consumed it
//   [16,67)   wqkvb (gemm1 B, 50.3MB) -> wob (32MB, written during attn
//             launch by trailing convert blocks — wqkvb dead after gemm1)
//   [48,52)   vtbuf (4MB, written after gemm1)
//   [67,91)   qkvb (gemm1 bf16 out, 24MB; attn reads Q from it directly)
//   [91,92)   cst rope table (1MB, float2[2048][64])
//   [107,111) kbuf (4MB)
// ---------------------------------------------------------------------------
extern "C" void kernel_launch(void* const* d_in, const int* in_sizes, int n_in,
                              void* d_out, int out_size, void* d_ws, size_t ws_size,
                              hipStream_t stream)
{
    const int*   positions = (const int*)  d_in[0];
    const float* hs        = (const float*)d_in[1];
    const float* wqkv      = (const float*)d_in[2];
    const float* wo        = (const float*)d_in[3];
    const float* gq        = (const float*)d_in[4];
    const float* gk        = (const float*)d_in[5];
    float* out = (float*)d_out;
    char* ws = (char*)d_ws;

    const size_t MB = 1ull << 20;
    short* hsb   = (short*)(ws);
    short* ctxb  = (short*)(ws);
    short* wqkvb = (short*)(ws + 16*MB);
    short* wob   = (short*)(ws + 16*MB);
    short* vtbuf = (short*)(ws + 48*MB);
    short* qkvb  = (short*)(ws + 67*MB);
    float* cst   = (float*)(ws + 91*MB);
    short* kbuf  = (short*)(ws + 107*MB);

    (void)in_sizes; (void)n_in; (void)out_size; (void)ws_size;

    convert_hs_wqkv<<<2112, 256, 0, stream>>>(hs, hsb, wqkv, wqkvb,
                                              positions, cst);
    gemm192<short><<<dim3(NQKV/192, S_LEN/128), 256, 0, stream>>>(
            hsb, wqkvb, qkvb, S_LEN, NQKV, HID);
    post_gemm1_fused<<<2560, 256, 0, stream>>>(
            qkvb, cst, gk, kbuf, vtbuf);
    attn_kernel<<<dim3(2560), 256, 0, stream>>>(
            wo, wob, qkvb, cst, gq, kbuf, vtbuf, ctxb);
    gemm_bt<float><<<dim3(HID/128, S_LEN/128), 256, 0, stream>>>(
            ctxb, wob, out, S_LEN, HID, HID);
}

// Round 16
// 286.145 us; speedup vs baseline: 1.1015x; 1.0008x over previous
//
#include <hip/hip_runtime.h>
#include <hip/hip_bf16.h>

// Problem constants
#define S_LEN 2048
#define HID   4096
#define NH    32
#define NKV   8
#define DH    128
#define NQKV  ((NH + 2*NKV) * DH)   // 6144

typedef __attribute__((ext_vector_type(8))) short s16x8;
typedef __attribute__((ext_vector_type(4))) short s16x4;
typedef __attribute__((ext_vector_type(4))) float f32x4;

__device__ __forceinline__ short f2bf(float x) {
    union { __hip_bfloat16 b; short s; } u;
    u.b = __float2bfloat16(x);
    return u.s;
}
__device__ __forceinline__ float bf2f(short s) {
    union { unsigned int u; float f; } v;
    v.u = ((unsigned int)(unsigned short)s) << 16;
    return v.f;
}

// async global->LDS, 16B per lane; lds dest = wave-uniform base + lane*16
__device__ __forceinline__ void gload16(const void* g, void* l) {
    __builtin_amdgcn_global_load_lds(
        (const __attribute__((address_space(1))) void*)g,
        (__attribute__((address_space(3))) void*)l,
        16, 0, 0);
}

__device__ __forceinline__ void cstore(float* p, float v) { *p = v; }
__device__ __forceinline__ void cstore(short* p, float v) { *p = f2bf(v); }

#define ROPE_C (13.287712379549449f / 64.0f)

// ---------------------------------------------------------------------------
// conversion kernel (R8-measured) + R15 rope table.
// blocks [0,1536): wqkv f32->bf16 LINEAR (gemm1 B).
// blocks [1536,2048): hs f32->bf16 PERMUTED into MFMA A-fragment order.
// blocks [2048,2112): cos/sin table cst[s][j<64] (float2, 1MB) — built once
// at full parallelism with the bit-identical expression (R14 post-mortem:
// trig in attn's prologue at 1/16 parallelism cost +35us).
// ---------------------------------------------------------------------------
__global__ __launch_bounds__(256) void convert_hs_wqkv(
        const float* __restrict__ hs, short* __restrict__ hsp,
        const float* __restrict__ wq, short* __restrict__ wqb,
        const int* __restrict__ pos, float* __restrict__ cst)
{
    const int bid = blockIdx.x;
    if (bid < 1536) {
        const long n = (long)NQKV * HID;
        long i0 = ((long)bid * 256 + threadIdx.x) * 4;
        long stride = 1536L * 256 * 4;
        for (long i = i0; i < n; i += stride) {
            float4 v = *(const float4*)(wq + i);
            s16x4 o;
            o[0] = f2bf(v.x); o[1] = f2bf(v.y); o[2] = f2bf(v.z); o[3] = f2bf(v.w);
            *(s16x4*)(wqb + i) = o;
        }
        return;
    }
    if (bid < 2048) {
        // hs permute: 1M 16B-chunks; c = (m16*128 + k32)*64 + lane
        const int nchunk = (S_LEN / 16) * (HID / 32) * 64;   // 1,048,576
        for (int c = (bid - 1536) * 256 + threadIdx.x; c < nchunk; c += 512 * 256) {
            int lane = c & 63, k32 = (c >> 6) & 127, m16 = c >> 13;
            int row = m16 * 16 + (lane & 15);
            int k   = k32 * 32 + (lane >> 4) * 8;
            const float4* p = (const float4*)(hs + (long)row * HID + k);
            float4 v0 = p[0], v1 = p[1];
            s16x8 o;
            o[0] = f2bf(v0.x); o[1] = f2bf(v0.y); o[2] = f2bf(v0.z); o[3] = f2bf(v0.w);
            o[4] = f2bf(v1.x); o[5] = f2bf(v1.y); o[6] = f2bf(v1.z); o[7] = f2bf(v1.w);
            *(s16x8*)(hsp + (long)c * 8) = o;
        }
        return;
    }
    // rope table: idx in [0,16384); s = idx>>3, j = (idx&7)*8 .. +7
    const int idx = (bid - 2048) * 256 + threadIdx.x;
    const int s = idx >> 3, j0 = (idx & 7) * 8;
    const float po = (float)pos[s];
#pragma unroll
    for (int jj = 0; jj < 8; ++jj) {
        int j = j0 + jj;
        float ang = po * exp2f(-(float)j * ROPE_C);
        float2 cs;
        cs.x = cosf(ang);
        cs.y = sinf(ang);
        *(float2*)(cst + ((long)s * 64 + j) * 2) = cs;
    }
}

// ---------------------------------------------------------------------------
// gemm1 (R7/R11-measured, 98.5us, MfmaUtil 45.9 — best gemm192 variant):
// 128x192-tile bf16 GEMM, C = A * B^T.  A read DIRECTLY from global in
// fragment layout (hsp) — LDS holds B only (2 x 24KB).  One barrier/tile.
// NOTE (R1-R10): seven structural variants all pinned at MfmaUtil 44-46%
// — plateau is structural for this tile family; gemm1 closed.
// ---------------------------------------------------------------------------
template <typename OT>
__global__ __launch_bounds__(256, 2) void gemm192(
        const short* __restrict__ Ap, const short* __restrict__ B,
        OT* __restrict__ C, int M, int N, int K)
{
    __shared__ char lds[49152];   // B only: 2 slots x 24KB
    const int t = threadIdx.x;
    const int w = t >> 6, l = t & 63, g = l >> 4, q16 = l & 15;
    const int wm = w >> 1, wn = w & 1;       // wave grid 2(M) x 2(N)
    const int bx = blockIdx.x, by = blockIdx.y;
    const int NT = K >> 6;                   // 64 at K=4096 (even)

    // B staging global byte offsets (chunk pre-swizzled)
    const int srow = t >> 3;
    const int schunk = (t & 7) ^ (srow & 7);
    unsigned goffB[6];
#pragma unroll
    for (int i = 0; i < 6; ++i)
        goffB[i] = (unsigned)(((bx * 192 + i * 32 + srow) * K) * 2 + schunk * 16);
    const int dstw = w * 1024;

    auto STAGE = [&](int kt) {               // 6 DMA: B 24KB
        char* dB = lds + (kt & 1) * 24576 + dstw;
        const unsigned kb = (unsigned)kt * 128;
#pragma unroll
        for (int i = 0; i < 6; ++i)
            gload16((const char*)B + (goffB[i] + kb), dB + i * 4096);
    };

    // A fragment global byte bases: ((m16*128 + k32)*64 + l)*16
    unsigned aBase[4];
#pragma unroll
    for (int mi = 0; mi < 4; ++mi)
        aBase[mi] = ((unsigned)((by * 8 + wm * 4 + mi) * 128) * 64 + (unsigned)l) * 16;

    // B LDS read offsets (row&7 == q16&7)
    int boff[6];
#pragma unroll
    for (int ni = 0; ni < 6; ++ni) boff[ni] = (wn * 96 + ni * 16 + q16) * 128;
    const int sw0 = ((g) ^ (q16 & 7)) << 4;
    const int sw1 = ((4 + g) ^ (q16 & 7)) << 4;

    f32x4 acc[4][6] = {};
    s16x8 aE[4][2], aO[4][2], b0E[2][2], b0O[2][2], b1[4][2];

    // prologue: STAGE(0) -> A(0) loads -> STAGE(1); vmcnt(6) drains
    // STAGE(0)+A(0), keeps STAGE(1) flying; barrier publishes B(0).
    STAGE(0);
    __builtin_amdgcn_sched_barrier(0);
#pragma unroll
    for (int mi = 0; mi < 4; ++mi)
#pragma unroll
        for (int kk = 0; kk < 2; ++kk)
            aE[mi][kk] = *(const s16x8*)((const char*)Ap + aBase[mi] + kk * 1024);
    __builtin_amdgcn_sched_barrier(0);
    STAGE(1);
    asm volatile("s_waitcnt vmcnt(6)" ::: "memory");
    __builtin_amdgcn_s_barrier();
    {
        const char* B0 = lds;
#pragma unroll
        for (int ni = 0; ni < 2; ++ni) {
            b0E[ni][0] = *(const s16x8*)(B0 + boff[ni] + sw0);
            b0E[ni][1] = *(const s16x8*)(B0 + boff[ni] + sw1);
        }
        asm volatile("s_waitcnt lgkmcnt(0)" ::: "memory");
        __builtin_amdgcn_sched_barrier(0);
    }

#define GB(KT, AC, AN, B0C, B0N, PAR) do {                                    \
    /* 1. b1(t) ds_reads; M0 on pre-loaded regs (zero wait) */                \
    const char* Bc_ = lds + (PAR) * 24576;                                    \
    _Pragma("unroll")                                                         \
    for (int ni = 0; ni < 4; ++ni) {                                          \
        b1[ni][0] = *(const s16x8*)(Bc_ + boff[2 + ni] + sw0);                \
        b1[ni][1] = *(const s16x8*)(Bc_ + boff[2 + ni] + sw1);                \
    }                                                                         \
    __builtin_amdgcn_sched_barrier(0);                                        \
    __builtin_amdgcn_s_setprio(1);                                            \
    _Pragma("unroll")                                                         \
    for (int mi = 0; mi < 4; ++mi)                                            \
    _Pragma("unroll")                                                         \
    for (int ni = 0; ni < 2; ++ni)                                            \
    _Pragma("unroll")                                                         \
    for (int kk = 0; kk < 2; ++kk)                                            \
        acc[mi][ni] = __builtin_amdgcn_mfma_f32_16x16x32_bf16(                \
                AC[mi][kk], B0C[ni][kk], acc[mi][ni], 0, 0, 0);               \
    __builtin_amdgcn_s_setprio(0);                                            \
    /* 2. gates + the ONE barrier: slot t free, B(t+1) published */           \
    asm volatile("s_waitcnt lgkmcnt(0)" ::: "memory");                        \
    __builtin_amdgcn_sched_barrier(0);                                        \
    asm volatile("s_waitcnt vmcnt(0)" ::: "memory");                          \
    __builtin_amdgcn_s_barrier();                                             \
    /* 3. A(t+1) frag loads FIRST, then STAGE(t+2), then b0(t+1) reads */     \
    if ((KT) + 1 < NT) {                                                      \
        _Pragma("unroll")                                                     \
        for (int mi = 0; mi < 4; ++mi)                                        \
        _Pragma("unroll")                                                     \
        for (int kk = 0; kk < 2; ++kk)                                        \
            AN[mi][kk] = *(const s16x8*)((const char*)Ap + aBase[mi]          \
                    + (((KT) + 1) * 2 + kk) * 1024);                          \
    }                                                                         \
    __builtin_amdgcn_sched_barrier(0);                                        \
    if ((KT) + 2 < NT) STAGE((KT) + 2);                                       \
    if ((KT) + 1 < NT) {                                                      \
        const char* Bn_ = lds + ((PAR) ^ 1) * 24576;                          \
        _Pragma("unroll")                                                     \
        for (int ni = 0; ni < 2; ++ni) {                                      \
            B0N[ni][0] = *(const s16x8*)(Bn_ + boff[ni] + sw0);               \
            B0N[ni][1] = *(const s16x8*)(Bn_ + boff[ni] + sw1);               \
        }                                                                     \
    }                                                                         \
    __builtin_amdgcn_sched_barrier(0);                                        \
    /* 4. M1 covers step-3 latency */                                         \
    __builtin_amdgcn_s_setprio(1);                                            \
    _Pragma("unroll")                                                         \
    for (int mi = 0; mi < 4; ++mi)                                            \
    _Pragma("unroll")                                                         \
    for (int ni = 0; ni < 4; ++ni)                                            \
    _Pragma("unroll")                                                         \
    for (int kk = 0; kk < 2; ++kk)                                            \
        acc[mi][2 + ni] = __builtin_amdgcn_mfma_f32_16x16x32_bf16(            \
                AC[mi][kk], b1[ni][kk], acc[mi][2 + ni], 0, 0, 0);            \
    __builtin_amdgcn_s_setprio(0);                                            \
    /* 5. end gates: b0(t+1) in regs; A(t+1) drained, STAGE(t+2) flies */     \
    asm volatile("s_waitcnt lgkmcnt(0)" ::: "memory");                        \
    __builtin_amdgcn_sched_barrier(0);                                        \
    if ((KT) + 2 < NT) asm volatile("s_waitcnt vmcnt(6)" ::: "memory");       \
    else               asm volatile("s_waitcnt vmcnt(0)" ::: "memory");       \
    __builtin_amdgcn_sched_barrier(0);                                        \
} while (0)

    for (int kt = 0; kt < NT; kt += 2) {
        GB(kt,     aE, aO, b0E, b0O, 0);
        GB(kt + 1, aO, aE, b0O, b0E, 1);
    }
#undef GB

    // epilogue: D col = lane&15, row = (lane>>4)*4 + r
#pragma unroll
    for (int mi = 0; mi < 4; ++mi) {
        long row = (long)by * 128 + wm * 64 + mi * 16 + g * 4;
#pragma unroll
        for (int ni = 0; ni < 6; ++ni) {
            long col = (long)bx * 192 + wn * 96 + ni * 16 + q16;
            f32x4 v = acc[mi][ni];
#pragma unroll
            for (int r = 0; r < 4; ++r)
                cstore(&C[(row + r) * (long)N + col], v[r]);
        }
    }
}

// ---------------------------------------------------------------------------
// gemm2: bf16 GEMM, C[M][N] = A[M][K] * B[N][K]^T.  R5 state (kept): 128x128
// tile, 256 threads (4 waves, 2Mx2N, 64x64/wave), counted lgkmcnt(4) gate,
// A-frag readahead dbuf, one barrier per K-tile, 2 blocks/CU.
// ---------------------------------------------------------------------------
template <typename OT>
__global__ __launch_bounds__(256, 2) void gemm_bt(
        const short* __restrict__ A, const short* __restrict__ B,
        OT* __restrict__ C, int M, int N, int K)
{
    __shared__ char lds[65536];   // A: 2 x 16KB at [0,32K); B: 2 x 16KB at [32K,64K)
    const int t = threadIdx.x;
    const int w = t >> 6, l = t & 63, g = l >> 4, q16 = l & 15;
    const int wm = w >> 1, wn = w & 1;       // wave grid 2(M) x 2(N)
    const int bx = blockIdx.x, by = blockIdx.y;
    const int NT = K >> 6;                   // 64 at K=4096 (even)

    // staging global byte offsets (chunk pre-swizzled)
    const int srow = t >> 3;                 // 0..31 within a 32-row band
    const int schunk = (t & 7) ^ (srow & 7);
    unsigned goffA[4], goffB[4];
#pragma unroll
    for (int i = 0; i < 4; ++i) {
        goffA[i] = (unsigned)(((by * 128 + i * 32 + srow) * K) * 2 + schunk * 16);
        goffB[i] = (unsigned)(((bx * 128 + i * 32 + srow) * K) * 2 + schunk * 16);
    }
    const int dstw = w * 1024;               // wave-uniform dest base part

    auto STAGE = [&](int kt) {               // 8 DMA instrs: A 16KB + B 16KB
        const int par = kt & 1;
        char* dA = lds + par * 16384 + dstw;
        char* dB = lds + 32768 + par * 16384 + dstw;
        const unsigned kb = (unsigned)kt * 128;
#pragma unroll
        for (int i = 0; i < 4; ++i) {
            gload16((const char*)A + (goffA[i] + kb), dA + i * 4096);
            gload16((const char*)B + (goffB[i] + kb), dB + i * 4096);
        }
    };

    // LDS read offsets (row&7 == q16&7 everywhere)
    int aoff[4], boff[4];
#pragma unroll
    for (int i = 0; i < 4; ++i) {
        aoff[i] = (wm * 64 + i * 16 + q16) * 128;
        boff[i] = (wn * 64 + i * 16 + q16) * 128;
    }
    const int sw0 = ((g) ^ (q16 & 7)) << 4;
    const int sw1 = ((4 + g) ^ (q16 & 7)) << 4;

    f32x4 acc[4][4] = {};
    s16x8 aE[4][2], aO[4][2], bf[4][2];

    // prologue: stage tiles 0,1; publish tile0; read-ahead A(0) -> aE
    STAGE(0); STAGE(1);
    asm volatile("s_waitcnt vmcnt(8)" ::: "memory");
    __builtin_amdgcn_s_barrier();
    {
        const char* A0 = lds;
#pragma unroll
        for (int mi = 0; mi < 4; ++mi) {
            aE[mi][0] = *(const s16x8*)(A0 + aoff[mi] + sw0);
            aE[mi][1] = *(const s16x8*)(A0 + aoff[mi] + sw1);
        }
    }

#define GB(KT, AC, AN, PAR) do {                                              \
    const char* Bs_ = lds + 32768 + (PAR) * 16384;                            \
    _Pragma("unroll")                                                         \
    for (int ni = 0; ni < 4; ++ni) {                                          \
        bf[ni][0] = *(const s16x8*)(Bs_ + boff[ni] + sw0);                    \
        bf[ni][1] = *(const s16x8*)(Bs_ + boff[ni] + sw1);                    \
    }                                                                         \
    asm volatile("s_waitcnt lgkmcnt(4)" ::: "memory");  /* A + b01 done */    \
    __builtin_amdgcn_sched_barrier(0);                                        \
    __builtin_amdgcn_s_setprio(1);                                            \
    _Pragma("unroll")                                                         \
    for (int mi = 0; mi < 4; ++mi)                                            \
    _Pragma("unroll")                                                         \
    for (int ni = 0; ni < 2; ++ni)                                            \
    _Pragma("unroll")                                                         \
    for (int kk = 0; kk < 2; ++kk)                                            \
        acc[mi][ni] = __builtin_amdgcn_mfma_f32_16x16x32_bf16(                \
                AC[mi][kk], bf[ni][kk], acc[mi][ni], 0, 0, 0);                \
    __builtin_amdgcn_s_setprio(0);                                            \
    asm volatile("s_waitcnt lgkmcnt(0)" ::: "memory");  /* b23 done */        \
    __builtin_amdgcn_sched_barrier(0);                                        \
    asm volatile("s_waitcnt vmcnt(0)" ::: "memory");    /* t+1 resident */    \
    __builtin_amdgcn_s_barrier();   /* slot t free + tile t+1 published */    \
    if ((KT) + 2 < NT) STAGE((KT) + 2);                                       \
    if ((KT) + 1 < NT) {            /* read-ahead A(t+1) under M1 */          \
        const char* An_ = lds + (((PAR) ^ 1) * 16384);                        \
        _Pragma("unroll")                                                     \
        for (int mi = 0; mi < 4; ++mi) {                                      \
            AN[mi][0] = *(const s16x8*)(An_ + aoff[mi] + sw0);                \
            AN[mi][1] = *(const s16x8*)(An_ + aoff[mi] + sw1);                \
        }                                                                     \
    }                                                                         \
    __builtin_amdgcn_s_setprio(1);                                            \
    _Pragma("unroll")                                                         \
    for (int mi = 0; mi < 4; ++mi)                                            \
    _Pragma("unroll")                                                         \
    for (int ni = 0; ni < 2; ++ni)                                            \
    _Pragma("unroll")                                                         \
    for (int kk = 0; kk < 2; ++kk)                                            \
        acc[mi][2 + ni] = __builtin_amdgcn_mfma_f32_16x16x32_bf16(            \
                AC[mi][kk], bf[2 + ni][kk], acc[mi][2 + ni], 0, 0, 0);        \
    __builtin_amdgcn_s_setprio(0);                                            \
} while (0)

    for (int kt = 0; kt < NT; kt += 2) {
        GB(kt,     aE, aO, 0);
        GB(kt + 1, aO, aE, 1);
    }
#undef GB

    // epilogue: D col = lane&15, row = (lane>>4)*4 + r
#pragma unroll
    for (int mi = 0; mi < 4; ++mi) {
        long row = (long)by * 128 + wm * 64 + mi * 16 + g * 4;
#pragma unroll
        for (int ni = 0; ni < 4; ++ni) {
            long col = (long)bx * 128 + wn * 64 + ni * 16 + q16;
            f32x4 v = acc[mi][ni];
#pragma unroll
            for (int r = 0; r < 4; ++r)
                cstore(&C[(row + r) * (long)N + col], v[r]);
        }
    }
}

// ---------------------------------------------------------------------------
// Post-gemm1 kernel, R13/R15: Q norm+rope lives in attn; K-norm uses the
// rope TABLE (no trig).  Jobs:
//   blocks [0, 2048):       K RMSNorm+RoPE (block = seq pos, 8 K-slots)
//   blocks [2048, 2560):    V transpose
// ---------------------------------------------------------------------------
__global__ __launch_bounds__(256) void post_gemm1_fused(
        const short* __restrict__ qkvb, const float* __restrict__ cst,
        const float* __restrict__ gk,
        short* __restrict__ ko, short* __restrict__ vt)
{
    const int bid = blockIdx.x;

    if (bid < 2048) {
        // ---- K RMSNorm + RoPE: s = bid, slot = NH + (tid>>5) ----
        const int s = bid;
        const int slot = NH + (threadIdx.x >> 5);   // 32..39
        const int p = threadIdx.x & 31, d = p * 4;

        s16x4 xv = *(const s16x4*)(qkvb + (long)s * NQKV + slot * DH + d);
        float x[4];
#pragma unroll
        for (int r = 0; r < 4; ++r) x[r] = bf2f(xv[r]);

        float ss = x[0]*x[0] + x[1]*x[1] + x[2]*x[2] + x[3]*x[3];
#pragma unroll
        for (int o = 1; o < 32; o <<= 1) ss += __shfl_xor(ss, o);
        float rms = rsqrtf(ss * (1.0f / DH) + 1e-6f);

        float y[4];
#pragma unroll
        for (int r = 0; r < 4; ++r) y[r] = x[r] * rms * gk[d + r];

        float y2[4];
#pragma unroll
        for (int r = 0; r < 4; ++r) y2[r] = __shfl_xor(y[r], 16);

        const int jbase = d & 63;
        s16x4 ov;
#pragma unroll
        for (int r = 0; r < 4; ++r) {
            float2 cs = *(const float2*)(cst + ((long)s * 64 + jbase + r) * 2);
            float outv = (d < 64) ? (y[r] * cs.x - y2[r] * cs.y)
                                  : (y[r] * cs.x + y2[r] * cs.y);
            ov[r] = f2bf(outv);
        }
        *(s16x4*)(ko + ((long)s * NKV + (slot - NH)) * DH + d) = ov;
        return;
    }

    // ---- V transpose: qkvb v-slots -> vt[h][d][s], 64x64 LDS tiles ----
    __shared__ short tile[64][72];
    const int idx2 = bid - 2048;
    const int sb = idx2 & 31, db = (idx2 >> 5) & 1, h = idx2 >> 6;
    const int t = threadIdx.x;
#pragma unroll
    for (int i = 0; i < 2; ++i) {
        int c = i * 256 + t;
        int row = c >> 3, dc = (c & 7) * 8;
        const short* src = qkvb + (long)(sb*64 + row) * NQKV
                           + (NH + NKV + h) * DH + db*64 + dc;
        s16x8 x = *(const s16x8*)src;
#pragma unroll
        for (int jj = 0; jj < 8; ++jj) tile[row][dc + jj] = x[jj];
    }
    __syncthreads();
#pragma unroll
    for (int i = 0; i < 2; ++i) {
        int c = i * 256 + t;
        int dr = c >> 3, sc = (c & 7) * 8;
        s16x8 y;
#pragma unroll
        for (int jj = 0; jj < 8; ++jj) y[jj] = tile[sc + jj][dr];
        short* dst = vt + (long)(h*DH + db*64 + dr) * S_LEN + sb*64 + sc;
        *(s16x8*)dst = y;
    }
}

// ---------------------------------------------------------------------------
// stage one K tile [64][128] and one Vt tile [128][64] into LDS via
// global_load_lds, PRE-SWIZZLED global source (+ linear LDS dest).
// V staging is PREFETCH (fire-and-forget DMA a tile ahead).
// ---------------------------------------------------------------------------
__device__ __forceinline__ void stage_kv(const char* kgB, const char* vgB,
                                         int kt, int t, char* kd, char* vd)
{
    const int w = t >> 6;
#pragma unroll
    for (int ci = 0; ci < 4; ++ci) {
        int c = ci * 256 + t;
        int row = c >> 4, col16 = c & 15;
        const char* gk = kgB + (long)(kt*64 + row) * (NKV*DH*2)
                         + ((col16*16) ^ ((row & 7) << 4));
        gload16(gk, kd + ci*4096 + w*1024);
        int rowv = c >> 3, scol8 = c & 7;
        const char* gv = vgB + (long)rowv * (S_LEN*2) + kt*128
                         + ((scol8*16) ^ ((rowv & 7) << 4));
        gload16(gv, vd + ci*4096 + w*1024);
    }
}

// ---------------------------------------------------------------------------
// Causal GQA flash attention, v12 + R12 (wo-convert tail blocks) + R15
// (Q RMSNorm+RoPE fused with TABLE-based rope) + R16 (coalesced ctx write:
// the old epilogue issued 64 scalar 2B stores/thread in 32B segments ->
// 2x HBM write amplification [+16MB].  New epilogue bounces the 128x128
// bf16 output tile through Kl (32KB, free after the loop: last iteration
// prefetches nothing and its __syncthreads drains all DMA), then streams
// out with 16-lane x 16B = 256B fully-coalesced row stores).
// ---------------------------------------------------------------------------
__global__ __launch_bounds__(256, 2) void attn_kernel(
        const float* __restrict__ wo, short* __restrict__ wob,
        const short* __restrict__ qkvb, const float* __restrict__ cst,
        const float* __restrict__ gq,
        const short* __restrict__ kg, const short* __restrict__ vtg,
        short* __restrict__ ctx)
{
    const int bx = blockIdx.x;       // [0,512) attn; [512,2560) wo-convert
    if (bx >= 512) {
        const long n = (long)HID * (NH * DH);
        long i0 = ((long)(bx - 512) * 256 + threadIdx.x) * 4;
        long stride = 2048L * 256 * 4;
        for (long i = i0; i < n; i += stride) {
            float4 v = *(const float4*)(wo + i);
            s16x4 o;
            o[0] = f2bf(v.x); o[1] = f2bf(v.y); o[2] = f2bf(v.z); o[3] = f2bf(v.w);
            *(s16x4*)(wob + i) = o;
        }
        return;
    }

    const int h  = bx & 31;          // head
    const int slot = bx >> 5;        // 0..15
    const int qb = (slot < 8) ? slot : 23 - slot;   // complementary pairing
    const int kvh = h >> 2;          // GQA: rep=4
    const int t = threadIdx.x, w = t >> 6, l = t & 63, g = l >> 4, q16 = l & 15;

    __shared__ char Kl[2][16384];    // [kv64][d128] bf16, swizzled
    __shared__ char Vl[2][16384];    // [d128][kv64] bf16, swizzled
    __shared__ short Pl[4][32 * 64]; // per-wave P[32 q][64 kv], swizzled

    const float scale = 0.08838834764831845f;  // 1/sqrt(128)
    const char* kgB = (const char*)kg + (long)kvh * DH * 2;
    const char* vgB = (const char*)vtg + (long)kvh * DH * (long)S_LEN * 2;

    const int nt = 2 * qb + 2;               // kv-tiles of 64
    int qrow[2];
    qrow[0] = qb*128 + w*32 + q16;
    qrow[1] = qrow[0] + 16;

    // start K/V staging FIRST — Q norm/rope hides under its latency
    stage_kv(kgB, vgB, 0, t, Kl[0], Vl[0]);

    // ---- R15 fused Q load + RMSNorm + table-RoPE (loads + FMA only) ----
    s16x8 qf[2][4];
#pragma unroll
    for (int s = 0; s < 2; ++s) {
        const short* qptr = qkvb + (long)qrow[s] * NQKV + h * DH;
        s16x8 v0 = *(const s16x8*)(qptr + 0*32 + g*8);
        s16x8 v1 = *(const s16x8*)(qptr + 1*32 + g*8);
        s16x8 v2 = *(const s16x8*)(qptr + 2*32 + g*8);
        s16x8 v3 = *(const s16x8*)(qptr + 3*32 + g*8);
        float ssum = 0.f;
#pragma unroll
        for (int j = 0; j < 8; ++j) {
            float a = bf2f(v0[j]), b = bf2f(v1[j]);
            float c2 = bf2f(v2[j]), d2 = bf2f(v3[j]);
            ssum += a*a + b*b + c2*c2 + d2*d2;
        }
        ssum += __shfl_xor(ssum, 16);
        ssum += __shfl_xor(ssum, 32);
        float rms = rsqrtf(ssum * (1.0f / DH) + 1e-6f);
        const float* csp = cst + (long)qrow[s] * 128;   // float2 cst[..][64]
        s16x8 q0, q1, q2, q3;   // named single vectors: SROA-safe inserts
#pragma unroll
        for (int j = 0; j < 8; ++j) {
            int jb0 = g*8 + j;                 // dk=0 plane, d in [0,32)
            float2 cs0 = *(const float2*)(csp + jb0 * 2);
            float y0 = bf2f(v0[j]) * rms * gq[jb0];
            float y2 = bf2f(v2[j]) * rms * gq[jb0 + 64];
            q0[j] = f2bf(y0 * cs0.x - y2 * cs0.y);
            q2[j] = f2bf(y2 * cs0.x + y0 * cs0.y);
            int jb1 = 32 + g*8 + j;            // dk=1 plane, d in [32,64)
            float2 cs1 = *(const float2*)(csp + jb1 * 2);
            float y1 = bf2f(v1[j]) * rms * gq[jb1];
            float y3 = bf2f(v3[j]) * rms * gq[jb1 + 64];
            q1[j] = f2bf(y1 * cs1.x - y3 * cs1.y);
            q3[j] = f2bf(y3 * cs1.x + y1 * cs1.y);
        }
        qf[s][0] = q0; qf[s][1] = q1; qf[s][2] = q2; qf[s][3] = q3;
    }

    f32x4 oacc[2][8] = {};
    float m_run[2] = {-1e30f, -1e30f}, l_run[2] = {0.f, 0.f};

    __syncthreads();   // drain vmcnt -> buf0 ready

    for (int kt = 0; kt < nt; ++kt) {
        const int b = kt & 1;
        if (kt + 1 < nt)   // prefetch next tile into other buffer (async)
            stage_kv(kgB, vgB, kt + 1, t, Kl[b ^ 1], Vl[b ^ 1]);
        const char* kb = Kl[b];
        const char* vbb = Vl[b];

        // ---- QK^T swapped: S^T[kv][q] = K * Q^T; K-frags serve both s
        f32x4 sacc[2][4] = {};
        __builtin_amdgcn_s_setprio(1);
#pragma unroll
        for (int m = 0; m < 4; ++m) {
            int kvr = m*16 + q16;
            s16x8 af[4];
#pragma unroll
            for (int dk = 0; dk < 4; ++dk) {
                int byte = (kvr*256 + (dk*32 + g*8)*2) ^ ((kvr & 7) << 4);
                af[dk] = *(const s16x8*)(kb + byte);
            }
#pragma unroll
            for (int s = 0; s < 2; ++s)
#pragma unroll
                for (int dk = 0; dk < 4; ++dk)
                    sacc[s][m] = __builtin_amdgcn_mfma_f32_16x16x32_bf16(
                            af[dk], qf[s][dk], sacc[s][m], 0,0,0);
        }
        __builtin_amdgcn_s_setprio(0);

        // ---- online softmax; lane owns q-columns qrow[0], qrow[1] ----
        const bool diag = (kt >= 2*qb);      // last two tiles straddle diag
        float mx[2];
#pragma unroll
        for (int s = 0; s < 2; ++s) {
            mx[s] = -1e30f;
#pragma unroll
            for (int m = 0; m < 4; ++m)
#pragma unroll
                for (int r = 0; r < 4; ++r) {
                    float x = sacc[s][m][r] * scale;
                    if (diag) {
                        int kv = kt*64 + m*16 + g*4 + r;
                        if (kv > qrow[s]) x = -1e30f;
                    }
                    sacc[s][m][r] = x;
                    mx[s] = fmaxf(mx[s], x);
                }
            mx[s] = fmaxf(mx[s], __shfl_xor(mx[s], 16));
            mx[s] = fmaxf(mx[s], __shfl_xor(mx[s], 32));
        }
        // defer-max: only rescale when max grew by > 8 somewhere (T13)
        if (__any((mx[0] > m_run[0] + 8.f) || (mx[1] > m_run[1] + 8.f))) {
#pragma unroll
            for (int s = 0; s < 2; ++s) {
                float m_new = fmaxf(m_run[s], mx[s]);
                float corr = __expf(m_run[s] - m_new);
                l_run[s] *= corr;
                m_run[s] = m_new;
                float rf[4];
#pragma unroll
                for (int r = 0; r < 4; ++r)
                    rf[r] = __shfl(corr, (g << 4) | (g*4 + r));
#pragma unroll
                for (int nf = 0; nf < 8; ++nf)
#pragma unroll
                    for (int r = 0; r < 4; ++r) oacc[s][nf][r] *= rf[r];
            }
        }
        // exp + pack to bf16 + LDS write (P bounded by e^8 when deferred)
#pragma unroll
        for (int s = 0; s < 2; ++s) {
            float psum = 0.f;
#pragma unroll
            for (int m = 0; m < 4; ++m) {
                s16x4 pk;
#pragma unroll
                for (int r = 0; r < 4; ++r) {
                    float e = __expf(sacc[s][m][r] - m_run[s]);
                    psum += e;
                    pk[r] = f2bf(e);
                }
                int byte = ((s*16 + q16)*128 + (m*16 + g*4)*2) ^ ((q16 & 7) << 4);
                *(s16x4*)((char*)&Pl[w][0] + byte) = pk;
            }
            psum += __shfl_xor(psum, 16);
            psum += __shfl_xor(psum, 32);
            l_run[s] += psum;
        }

        // ---- PV: O[q][d] += P[q][kv] * V[kv][d]; V-frags serve both s
        __builtin_amdgcn_s_setprio(1);
#pragma unroll
        for (int ks = 0; ks < 2; ++ks) {
            s16x8 pa[2];
#pragma unroll
            for (int s = 0; s < 2; ++s) {
                int pbyte = ((s*16 + q16)*128 + (ks*32 + g*8)*2) ^ ((q16 & 7) << 4);
                pa[s] = *(const s16x8*)((const char*)&Pl[w][0] + pbyte);
            }
#pragma unroll
            for (int nf = 0; nf < 8; ++nf) {
                int drow = nf*16 + q16;
                int vbyte = (drow*128 + (ks*32 + g*8)*2) ^ ((drow & 7) << 4);
                s16x8 vbf = *(const s16x8*)(vbb + vbyte);
#pragma unroll
                for (int s = 0; s < 2; ++s)
                    oacc[s][nf] = __builtin_amdgcn_mfma_f32_16x16x32_bf16(
                            pa[s], vbf, oacc[s][nf], 0,0,0);
            }
        }
        __builtin_amdgcn_s_setprio(0);
        __syncthreads();   // tile done; prefetched buffer complete
    }

    // ---- R16 epilogue: divide by l, bounce through LDS, coalesced write --
    // Kl[0..1] = 32KB = exactly the block's 128x128 bf16 output tile.
    // (Free: last loop iteration prefetches nothing; final __syncthreads
    //  drained all DMA and all waves' reads.)
    short* ot = (short*)&Kl[0][0];   // row-major [128][128] bf16
#pragma unroll
    for (int s = 0; s < 2; ++s) {
        float lr[4];
#pragma unroll
        for (int r = 0; r < 4; ++r)
            lr[r] = __shfl(l_run[s], (g << 4) | (g*4 + r));
#pragma unroll
        for (int nf = 0; nf < 8; ++nf)
#pragma unroll
            for (int r = 0; r < 4; ++r) {
                int row = w*32 + s*16 + g*4 + r;            // 0..127
                int col = nf*16 + q16;                       // 0..127
                ot[row * 128 + col] = f2bf(oacc[s][nf][r] / lr[r]);
            }
    }
    __syncthreads();
    // stream out: 8 passes; 16 lanes cover one 256B row -> full coalescing
#pragma unroll
    for (int p = 0; p < 8; ++p) {
        int row = p * 16 + (t >> 4);                         // 0..127
        int c8  = (t & 15) * 8;                              // col in shorts
        s16x8 v = *(const s16x8*)(ot + row * 128 + c8);
        *(s16x8*)(ctx + (long)(qb*128 + row) * (NH*DH) + h*DH + c8) = v;
    }
}

// ---------------------------------------------------------------------------
// Workspace layout (race-free, peak 111 MB):
//   [0,16)    hsb (gemm1 A, PERMUTED fragment layout, 16MB exactly)
//             -> ctxb (attn out) after gemm1 consumed it
//   [16,67)   wqkvb (gemm1 B, 50.3MB) -> wob (32MB, written during attn
//             launch by trailing convert blocks — wqkvb dead after gemm1)
//   [48,52)   vtbuf (4MB, written after gemm1)
//   [67,91)   qkvb (gemm1 bf16 out, 24MB; attn reads Q from it directly)
//   [91,92)   cst rope table (1MB, float2[2048][64])
//   [107,111) kbuf (4MB)
// ---------------------------------------------------------------------------
extern "C" void kernel_launch(void* const* d_in, const int* in_sizes, int n_in,
                              void* d_out, int out_size, void* d_ws, size_t ws_size,
                              hipStream_t stream)
{
    const int*   positions = (const int*)  d_in[0];
    const float* hs        = (const float*)d_in[1];
    const float* wqkv      = (const float*)d_in[2];
    const float* wo        = (const float*)d_in[3];
    const float* gq        = (const float*)d_in[4];
    const float* gk        = (const float*)d_in[5];
    float* out = (float*)d_out;
    char* ws = (char*)d_ws;

    const size_t MB = 1ull << 20;
    short* hsb   = (short*)(ws);
    short* ctxb  = (short*)(ws);
    short* wqkvb = (short*)(ws + 16*MB);
    short* wob   = (short*)(ws + 16*MB);
    short* vtbuf = (short*)(ws + 48*MB);
    short* qkvb  = (short*)(ws + 67*MB);
    float* cst   = (float*)(ws + 91*MB);
    short* kbuf  = (short*)(ws + 107*MB);

    (void)in_sizes; (void)n_in; (void)out_size; (void)ws_size;

    convert_hs_wqkv<<<2112, 256, 0, stream>>>(hs, hsb, wqkv, wqkvb,
                                              positions, cst);
    gemm192<short><<<dim3(NQKV/192, S_LEN/128), 256, 0, stream>>>(
            hsb, wqkvb, qkvb, S_LEN, NQKV, HID);
    post_gemm1_fused<<<2560, 256, 0, stream>>>(
            qkvb, cst, gk, kbuf, vtbuf);
    attn_kernel<<<dim3(2560), 256, 0, stream>>>(
            wo, wob, qkvb, cst, gq, kbuf, vtbuf, ctxb);
    gemm_bt<float><<<dim3(HID/128, S_LEN/128), 256, 0, stream>>>(
            ctxb, wob, out, S_LEN, HID, HID);
}